// Round 5
// baseline (161.384 us; speedup 1.0000x reference)
//
#include <hip/hip_runtime.h>

typedef __attribute__((ext_vector_type(8))) short short8;
typedef __attribute__((ext_vector_type(4))) float f32x4;

#define MFMA(a,b,c) __builtin_amdgcn_mfma_f32_16x16x32_bf16((a),(b),(c),0,0,0)

#define B_  2
#define S_  2048
#define D_  1024
#define H_  16
#define DK  64
#define KDIM 1024

typedef unsigned int u32;
typedef __attribute__((address_space(1))) const u32 gu32;
typedef __attribute__((address_space(3))) u32 lu32;

// async global->LDS, 16 B per lane; LDS dest = base + lane*16 (wave-uniform base)
__device__ __forceinline__ void gll16(const unsigned short* g, unsigned short* l){
  __builtin_amdgcn_global_load_lds((gu32*)g, (lu32*)l, 16, 0, 0);
}

__device__ __forceinline__ unsigned short f2bf(float f){
  unsigned int u = __float_as_uint(f);
  u += 0x7fffu + ((u >> 16) & 1u);   // RNE (finite inputs only)
  return (unsigned short)(u >> 16);
}

// pack two f32 -> two bf16 (round-half-up) in 3 VALU: 2 adds + v_perm_b32.
__device__ __forceinline__ u32 pkbf(float lo, float hi){
  u32 a = __float_as_uint(lo) + 0x8000u;
  u32 b = __float_as_uint(hi) + 0x8000u;
  return __builtin_amdgcn_perm(b, a, 0x07060302u);
}

// ---------------- fp32 -> bf16 convert, all 5 tensors in one launch ---------
__global__ void cvt_all(const float* __restrict__ x,  const float* __restrict__ qw,
                        const float* __restrict__ kw, const float* __restrict__ vw,
                        const float* __restrict__ ow,
                        unsigned short* __restrict__ xb,  unsigned short* __restrict__ wqb,
                        unsigned short* __restrict__ wkb, unsigned short* __restrict__ wvb,
                        unsigned short* __restrict__ wob,
                        int n4x, int n4w){
  int i = blockIdx.x * 256 + threadIdx.x;
  const float* src; unsigned short* dst; int n4;
  switch (blockIdx.y) {
    case 0:  src = x;  dst = xb;  n4 = n4x; break;
    case 1:  src = qw; dst = wqb; n4 = n4w; break;
    case 2:  src = kw; dst = wkb; n4 = n4w; break;
    case 3:  src = vw; dst = wvb; n4 = n4w; break;
    default: src = ow; dst = wob; n4 = n4w; break;
  }
  if (i >= n4) return;
  float4 f = reinterpret_cast<const float4*>(src)[i];
  ushort4 u;
  u.x = f2bf(f.x); u.y = f2bf(f.y); u.z = f2bf(f.z); u.w = f2bf(f.w);
  reinterpret_cast<ushort4*>(dst)[i] = u;
}

// ---------------- FUSED QKV projection (one pass over X) --------------------
// One block computes the 128x64 output tile for ALL THREE projections:
// stages its X-tile ONCE + Wq/Wk/Wv tiles.  Per K-step per wave: 48 MFMA,
// 20 ds_read_b128, 10 global_load_lds.  LDS 80 KB -> 2 blocks/CU; grid 512.
// Chunk-XOR swizzle (conflict-free, verified R1) + depth-2 counted-vmcnt
// pipeline (verified R2): no vmcnt(0) drain in steady state.
struct FragsQKV { short8 a0[4], a1[4], b0[3][2], b1[3][2]; };

__global__ __launch_bounds__(256, 2) void gemm_qkv(
    const unsigned short* __restrict__ X,
    const unsigned short* __restrict__ Wq,
    const unsigned short* __restrict__ Wk,
    const unsigned short* __restrict__ Wv,
    unsigned short* __restrict__ Qo,
    unsigned short* __restrict__ Ko,
    unsigned short* __restrict__ Vo)
{
  const int n0 = blockIdx.x * 64;
  const int m0 = blockIdx.y * 128;

  __shared__ unsigned short As[2][128 * 64];      // 2 x 16 KiB
  __shared__ unsigned short Bs[2][3][64 * 64];    // 2 x 3 x 8 KiB

  const int tid  = threadIdx.x;
  const int wid  = tid >> 6, lane = tid & 63;
  const int wm   = (wid >> 1) * 64, wn = (wid & 1) * 32;
  const int lr   = lane & 15, c = lane >> 4;
  const int sw   = lr & 7;
  const int pc0  = (c ^ sw) * 8;               // k-half 0 chunk, shorts
  const int pc1  = ((c ^ 4) ^ sw) * 8;         // k-half 1 chunk, shorts

  const int srow = lane >> 3;                  // 0..7
  const int scol = ((lane & 7) ^ srow) * 8;    // inverse-swizzled source col
  const unsigned short* gA  = X  + (size_t)(m0 + wid * 32 + srow) * KDIM + scol;
  const unsigned short* gBq = Wq + (size_t)(n0 + wid * 16 + srow) * KDIM + scol;
  const unsigned short* gBk = Wk + (size_t)(n0 + wid * 16 + srow) * KDIM + scol;
  const unsigned short* gBv = Wv + (size_t)(n0 + wid * 16 + srow) * KDIM + scol;

  auto stage = [&](int buf, int k0) {
    unsigned short* la  = &As[buf][(wid * 32) * 64];
    unsigned short* lbq = &Bs[buf][0][(wid * 16) * 64];
    unsigned short* lbk = &Bs[buf][1][(wid * 16) * 64];
    unsigned short* lbv = &Bs[buf][2][(wid * 16) * 64];
#pragma unroll
    for (int i = 0; i < 4; i++) gll16(gA + (size_t)(i * 8) * KDIM + k0, la + i * 512);
#pragma unroll
    for (int i = 0; i < 2; i++) gll16(gBq + (size_t)(i * 8) * KDIM + k0, lbq + i * 512);
#pragma unroll
    for (int i = 0; i < 2; i++) gll16(gBk + (size_t)(i * 8) * KDIM + k0, lbk + i * 512);
#pragma unroll
    for (int i = 0; i < 2; i++) gll16(gBv + (size_t)(i * 8) * KDIM + k0, lbv + i * 512);
  };

  auto ldfr = [&](int buf, FragsQKV& f) {
    const unsigned short* AS = As[buf];
#pragma unroll
    for (int i = 0; i < 4; i++) {
      f.a0[i] = *(const short8*)&AS[(wm + i * 16 + lr) * 64 + pc0];
      f.a1[i] = *(const short8*)&AS[(wm + i * 16 + lr) * 64 + pc1];
    }
#pragma unroll
    for (int z = 0; z < 3; z++) {
      const unsigned short* BS = Bs[buf][z];
#pragma unroll
      for (int j = 0; j < 2; j++) {
        f.b0[z][j] = *(const short8*)&BS[(wn + j * 16 + lr) * 64 + pc0];
        f.b1[z][j] = *(const short8*)&BS[(wn + j * 16 + lr) * 64 + pc1];
      }
    }
  };

  f32x4 acc[3][4][2];
  const f32x4 z4 = {0.f, 0.f, 0.f, 0.f};
#pragma unroll
  for (int z = 0; z < 3; z++)
    for (int i = 0; i < 4; i++)
      for (int j = 0; j < 2; j++) acc[z][i][j] = z4;

  auto mfmas = [&](const FragsQKV& f) {
#pragma unroll
    for (int z = 0; z < 3; z++) {
      if (z == 2) {
#pragma unroll
        for (int i = 0; i < 4; i++)
#pragma unroll
          for (int j = 0; j < 2; j++) {
            acc[z][i][j] = MFMA(f.b0[z][j], f.a0[i], acc[z][i][j]);  // V: rows=W-dim
            acc[z][i][j] = MFMA(f.b1[z][j], f.a1[i], acc[z][i][j]);
          }
      } else {
#pragma unroll
        for (int i = 0; i < 4; i++)
#pragma unroll
          for (int j = 0; j < 2; j++) {
            acc[z][i][j] = MFMA(f.a0[i], f.b0[z][j], acc[z][i][j]);
            acc[z][i][j] = MFMA(f.a1[i], f.b1[z][j], acc[z][i][j]);
          }
      }
    }
  };

  // prologue: two tiles in flight (20 loads)
  stage(0, 0);
  stage(1, 64);

  FragsQKV f;
  const int NT = KDIM / 64;                    // 16
  for (int t = 0; t < NT - 2; ++t) {
    const int buf = t & 1;
    asm volatile("s_waitcnt vmcnt(10)" ::: "memory");  // my stage(t) landed
    __builtin_amdgcn_s_barrier();                       // everyone's landed
    asm volatile("" ::: "memory");
    ldfr(buf, f);
    asm volatile("s_waitcnt lgkmcnt(0)" ::: "memory"); // my reads serviced
    __builtin_amdgcn_sched_barrier(0);
    __builtin_amdgcn_s_barrier();                       // buf free to overwrite
    asm volatile("" ::: "memory");
    stage(buf, (t + 2) * 64);                           // 10 loads in flight
    __builtin_amdgcn_sched_barrier(0);
    mfmas(f);                                           // covers load latency
  }
  // t = NT-2: no further staging
  asm volatile("s_waitcnt vmcnt(10)" ::: "memory");
  __builtin_amdgcn_s_barrier();
  asm volatile("" ::: "memory");
  ldfr((NT - 2) & 1, f);
  mfmas(f);
  // t = NT-1: drain the last tile
  asm volatile("s_waitcnt vmcnt(0)" ::: "memory");
  __builtin_amdgcn_s_barrier();
  asm volatile("" ::: "memory");
  ldfr((NT - 1) & 1, f);
  mfmas(f);

  const int rbase = (lane >> 4) * 4;
  // z=0: Q (scaled), z=1: K, z=2: V^T
  for (int i = 0; i < 4; i++)
    for (int j = 0; j < 2; j++)
      for (int r = 0; r < 4; r++) {
        int m = m0 + wm + i * 16 + rbase + r;
        int n = n0 + wn + j * 16 + lr;
        int bb = m >> 11, s = m & 2047, h = n >> 6, d = n & 63;
        float vq = acc[0][i][j][r] * 0.18033688f;  // (1/sqrt(64))*log2(e)
        Qo[(((bb * H_ + h) * S_) + s) * DK + d] = f2bf(vq);
        Ko[(((bb * H_ + h) * S_) + s) * DK + d] = f2bf(acc[1][i][j][r]);
      }
  for (int i = 0; i < 4; i++)
    for (int j = 0; j < 2; j++)
      for (int r = 0; r < 4; r++) {
        int dfull = n0 + wn + j * 16 + rbase + r;   // W row (h,dk)
        int sfull = m0 + wm + i * 16 + lr;          // X row (b,s)
        int h = dfull >> 6, d = dfull & 63;
        int bb = sfull >> 11, s = sfull & 2047;
        Vo[(((bb * H_ + h) * DK) + d) * S_ + s] = f2bf(acc[2][i][j][r]);
      }
}

// ---------------- causal flash attention (R5: depth-2 counted pipeline) -----
// Q,K: [B,H,S,DK] bf16 (Q pre-scaled to exp2 domain); V: [B,H,DK,S] bf16.
// 8 waves / 512 threads (R3 structure: 16 q-rows per wave), but the K/V
// staging is a 3-buffer depth-2 counted-vmcnt pipeline instead of the
// ping-pong + full __syncthreads drain: steady state waits vmcnt(2) (tile t
// landed, t+1 in flight), barriers, stages t+2 into the freed buffer, then
// computes t.  Buffer safety: stage(t+2) overwrites buf[(t-1)%3]; its last
// readers finished compute(t-1) before this step's barrier.
// K/V tiles 64x64, rotation swizzle (phys 16B chunk c of row r holds logical
// chunk (c-r)&7).  LDS 66 KB -> 2 blocks/CU (= grid 512 residency).
__global__ __launch_bounds__(512, 4) void attn(
    const unsigned short* __restrict__ Q,
    const unsigned short* __restrict__ K,
    const unsigned short* __restrict__ V,
    unsigned short* __restrict__ O)
{
  const int h = blockIdx.y, b = blockIdx.z;
  const int qt = b ? (15 - blockIdx.x) : blockIdx.x;

  const unsigned short* __restrict__ Qh = Q + (size_t)((b * H_ + h) * S_) * DK;
  const unsigned short* __restrict__ Kh = K + (size_t)((b * H_ + h) * S_) * DK;
  const unsigned short* __restrict__ Vh = V + (size_t)((b * H_ + h) * DK) * S_;

  __shared__ unsigned short Ks[3][64 * 64];   // [key][d], swizzled chunks
  __shared__ unsigned short Vs[3][64 * 64];   // [d][key], swizzled chunks
  __shared__ unsigned short Ps[8][16][72];    // per-wave: [q][key] (padded)

  const int tid = threadIdx.x, wid = tid >> 6, lane = tid & 63;
  const int lr = lane & 15;
  const int row4 = (lane >> 4) * 4;
  const int q0 = qt * 128;
  const int qcol = q0 + wid * 16 + lr;
  const int qwmin = q0 + wid * 16;
  const int qwmax = qwmin + 15;
  const int lk = (lane >> 4) * 8;             // for Q/P fragments (unswizzled)

  // swizzled LDS read offsets (shorts): logical chunk c=(lane>>4), rot by row
  const int pc0 = (((lane >> 4) + lr) & 7) * 8;
  const int pc1 = (((lane >> 4) + 4 + lr) & 7) * 8;

  // staging: wave wid covers rows [8*wid, 8*wid+8) of both K and V tiles
  const int sr8 = lane >> 3;                  // 0..7 row within chunk
  const int sc8 = lane & 7;                   // physical chunk
  const int sg  = (sc8 - sr8) & 7;            // logical chunk to fetch
  const int stRow = wid * 8 + sr8;            // 0..63
  const unsigned short* gK = Kh + (size_t)stRow * DK + sg * 8;
  const unsigned short* gV = Vh + (size_t)stRow * S_ + sg * 8;
  unsigned short* kd[3] = {&Ks[0][wid * 8 * 64], &Ks[1][wid * 8 * 64], &Ks[2][wid * 8 * 64]};
  unsigned short* vd[3] = {&Vs[0][wid * 8 * 64], &Vs[1][wid * 8 * 64], &Vs[2][wid * 8 * 64]};

  const short ONE = (short)0x3F80;            // bf16 1.0
  const short8 ones = {ONE, ONE, ONE, ONE, ONE, ONE, ONE, ONE};

  short8 qf[2];
  qf[0] = *(const short8*)&Qh[(q0 + wid * 16 + lr) * DK + lk];
  qf[1] = *(const short8*)&Qh[(q0 + wid * 16 + lr) * DK + 32 + lk];

  const f32x4 z4 = {0.f, 0.f, 0.f, 0.f};
  f32x4 o[4];
  for (int i = 0; i < 4; i++) o[i] = z4;
  f32x4 rs = z4;                              // l(q=lr) on the MFMA pipe

  auto tile = [&](int k0, const unsigned short* KS, const unsigned short* VS){
    if (k0 > qwmax) return;                   // wave-uniform skip
    f32x4 sc[4];
    __builtin_amdgcn_s_setprio(1);
    for (int nt = 0; nt < 4; nt++) {
      short8 kb0 = *(const short8*)&KS[(nt * 16 + lr) * 64 + pc0];
      short8 kb1 = *(const short8*)&KS[(nt * 16 + lr) * 64 + pc1];
      f32x4 s = MFMA(kb0, qf[0], z4);
      sc[nt] = MFMA(kb1, qf[1], s);
    }
    __builtin_amdgcn_s_setprio(0);
    if (k0 + 63 > qwmin) {                    // diagonal region: mask key > q
      for (int nt = 0; nt < 4; nt++) {
        int kg = k0 + nt * 16 + row4;
        for (int r = 0; r < 4; r++)
          if (kg + r > qcol) sc[nt][r] = -INFINITY;
      }
    }
    for (int nt = 0; nt < 4; nt++) {
      float p0 = __builtin_amdgcn_exp2f(sc[nt][0]);
      float p1 = __builtin_amdgcn_exp2f(sc[nt][1]);
      float p2 = __builtin_amdgcn_exp2f(sc[nt][2]);
      float p3 = __builtin_amdgcn_exp2f(sc[nt][3]);
      uint2 pk;
      pk.x = pkbf(p0, p1);
      pk.y = pkbf(p2, p3);
      *(uint2*)&Ps[wid][lr][nt * 16 + row4] = pk;
    }
    short8 pf0 = *(const short8*)&Ps[wid][lr][lk];
    short8 pf1 = *(const short8*)&Ps[wid][lr][32 + lk];
    __builtin_amdgcn_s_setprio(1);
    rs = MFMA(ones, pf0, rs);
    rs = MFMA(ones, pf1, rs);
    for (int dt = 0; dt < 4; dt++) {
      short8 vb0 = *(const short8*)&VS[(dt * 16 + lr) * 64 + pc0];
      short8 vb1 = *(const short8*)&VS[(dt * 16 + lr) * 64 + pc1];
      o[dt] = MFMA(vb0, pf0, o[dt]);
      o[dt] = MFMA(vb1, pf1, o[dt]);
    }
    __builtin_amdgcn_s_setprio(0);
  };

  const int T = 2 * qt + 2;                   // number of 64-key tiles (>= 2)

  // prologue: tiles 0 and 1 in flight (2 gll16 each)
  gll16(gK,                     kd[0]);
  gll16(gV,                     vd[0]);
  gll16(gK + (size_t)64 * DK,   kd[1]);
  gll16(gV + 64,                vd[1]);

  for (int t = 0; t < T; ++t) {
    if (t < T - 1) asm volatile("s_waitcnt vmcnt(2)" ::: "memory");  // tile t landed
    else           asm volatile("s_waitcnt vmcnt(0)" ::: "memory");  // last tile
    __builtin_amdgcn_s_barrier();             // all waves' tile-t rows landed
    asm volatile("" ::: "memory");
    if (t + 2 < T) {                          // stage t+2 into freed buffer
      const int cbuf = (t + 2) % 3;
      gll16(gK + (size_t)((t + 2) * 64) * DK, kd[cbuf]);
      gll16(gV + (t + 2) * 64,                vd[cbuf]);
    }
    tile(t * 64, &Ks[t % 3][0], &Vs[t % 3][0]);
  }

  const float inv = 1.0f / rs[0];

  const int srow = q0 + wid * 16 + lr;
  for (int dt = 0; dt < 4; dt++) {
    uint2 pk;
    pk.x = pkbf(o[dt][0] * inv, o[dt][1] * inv);
    pk.y = pkbf(o[dt][2] * inv, o[dt][3] * inv);
    *(uint2*)&O[(size_t)(b * S_ + srow) * D_ + h * DK + dt * 16 + row4] = pk;
  }
}

struct Frags { short8 a0[4], a1[4], b0[2], b1[2]; };

// ---------------- output projection (counted-vmcnt pipeline, fp32 out) ------
__global__ __launch_bounds__(256) void gemm_oproj(
    const unsigned short* __restrict__ A,
    const unsigned short* __restrict__ W,
    float* __restrict__ out)
{
  const int n0 = blockIdx.x * 64;
  const int m0 = blockIdx.y * 128;

  __shared__ unsigned short As[2][128 * 64];
  __shared__ unsigned short Bs[2][64 * 64];

  const int tid  = threadIdx.x;
  const int wid  = tid >> 6, lane = tid & 63;
  const int wm   = (wid >> 1) * 64, wn = (wid & 1) * 32;
  const int lr   = lane & 15, c = lane >> 4;
  const int sw   = lr & 7;
  const int pc0  = (c ^ sw) * 8;
  const int pc1  = ((c ^ 4) ^ sw) * 8;

  const int srow = lane >> 3;
  const int scol = ((lane & 7) ^ srow) * 8;
  const unsigned short* gA = A + (size_t)(m0 + wid * 32 + srow) * KDIM + scol;
  const unsigned short* gB = W + (size_t)(n0 + wid * 16 + srow) * KDIM + scol;

  auto stage = [&](int buf, int k0) {
    unsigned short* la = &As[buf][(wid * 32) * 64];
    unsigned short* lb = &Bs[buf][(wid * 16) * 64];
#pragma unroll
    for (int i = 0; i < 4; i++) gll16(gA + (size_t)(i * 8) * KDIM + k0, la + i * 512);
#pragma unroll
    for (int i = 0; i < 2; i++) gll16(gB + (size_t)(i * 8) * KDIM + k0, lb + i * 512);
  };

  auto ldfr = [&](int buf, Frags& f) {
    const unsigned short* AS = As[buf];
    const unsigned short* BS = Bs[buf];
#pragma unroll
    for (int i = 0; i < 4; i++) {
      f.a0[i] = *(const short8*)&AS[(wm + i * 16 + lr) * 64 + pc0];
      f.a1[i] = *(const short8*)&AS[(wm + i * 16 + lr) * 64 + pc1];
    }
#pragma unroll
    for (int j = 0; j < 2; j++) {
      f.b0[j] = *(const short8*)&BS[(wn + j * 16 + lr) * 64 + pc0];
      f.b1[j] = *(const short8*)&BS[(wn + j * 16 + lr) * 64 + pc1];
    }
  };

  f32x4 acc[4][2];
  const f32x4 z4 = {0.f, 0.f, 0.f, 0.f};
  for (int i = 0; i < 4; i++)
    for (int j = 0; j < 2; j++) acc[i][j] = z4;

  auto mfmas = [&](const Frags& f) {
#pragma unroll
    for (int i = 0; i < 4; i++)
#pragma unroll
      for (int j = 0; j < 2; j++) {
        acc[i][j] = MFMA(f.a0[i], f.b0[j], acc[i][j]);
        acc[i][j] = MFMA(f.a1[i], f.b1[j], acc[i][j]);
      }
  };

  stage(0, 0);
  stage(1, 64);

  Frags f;
  const int NT = KDIM / 64;                    // 16
  for (int t = 0; t < NT - 2; ++t) {
    const int buf = t & 1;
    asm volatile("s_waitcnt vmcnt(6)" ::: "memory");
    __builtin_amdgcn_s_barrier();
    asm volatile("" ::: "memory");
    ldfr(buf, f);
    asm volatile("s_waitcnt lgkmcnt(0)" ::: "memory");
    __builtin_amdgcn_sched_barrier(0);
    __builtin_amdgcn_s_barrier();
    asm volatile("" ::: "memory");
    stage(buf, (t + 2) * 64);
    __builtin_amdgcn_sched_barrier(0);
    mfmas(f);
  }
  asm volatile("s_waitcnt vmcnt(6)" ::: "memory");
  __builtin_amdgcn_s_barrier();
  asm volatile("" ::: "memory");
  ldfr((NT - 2) & 1, f);
  mfmas(f);
  asm volatile("s_waitcnt vmcnt(0)" ::: "memory");
  __builtin_amdgcn_s_barrier();
  asm volatile("" ::: "memory");
  ldfr((NT - 1) & 1, f);
  mfmas(f);

  const int rbase = (lane >> 4) * 4;
  for (int i = 0; i < 4; i++)
    for (int j = 0; j < 2; j++)
      for (int r = 0; r < 4; r++) {
        int m = m0 + wm + i * 16 + rbase + r;
        int n = n0 + wn + j * 16 + lr;
        out[(size_t)m * D_ + n] = acc[i][j][r];
      }
}

extern "C" void kernel_launch(void* const* d_in, const int* in_sizes, int n_in,
                              void* d_out, int out_size, void* d_ws, size_t ws_size,
                              hipStream_t stream) {
  const float* x  = (const float*)d_in[0];
  const float* qw = (const float*)d_in[1];
  const float* kw = (const float*)d_in[2];
  const float* vw = (const float*)d_in[3];
  const float* ow = (const float*)d_in[4];
  float* out = (float*)d_out;

  char* ws = (char*)d_ws;
  size_t off = 0;
  auto alloc = [&](size_t bytes) -> void* {
    void* p = ws + off;
    off += (bytes + 255) & ~(size_t)255;
    return p;
  };
  const size_t XN = (size_t)B_ * S_ * D_;     // 4194304
  const size_t WN = (size_t)D_ * D_;          // 1048576
  unsigned short* xb  = (unsigned short*)alloc(XN * 2);
  unsigned short* wqb = (unsigned short*)alloc(WN * 2);
  unsigned short* wkb = (unsigned short*)alloc(WN * 2);
  unsigned short* wvb = (unsigned short*)alloc(WN * 2);
  unsigned short* wob = (unsigned short*)alloc(WN * 2);
  unsigned short* Qb  = (unsigned short*)alloc(XN * 2);
  unsigned short* Kb  = (unsigned short*)alloc(XN * 2);
  unsigned short* Vb  = (unsigned short*)alloc(XN * 2);
  unsigned short* Ob  = (unsigned short*)alloc(XN * 2);

  cvt_all<<<dim3((XN / 4 + 255) / 256, 5), dim3(256), 0, stream>>>(
      x, qw, kw, vw, ow, xb, wqb, wkb, wvb, wob, (int)(XN / 4), (int)(WN / 4));

  gemm_qkv<<<dim3(D_ / 64, (B_ * S_) / 128), dim3(256), 0, stream>>>(
      xb, wqb, wkb, wvb, Qb, Kb, Vb);

  attn<<<dim3(S_ / 128, H_, B_), dim3(512), 0, stream>>>(Qb, Kb, Vb, Ob);

  gemm_oproj<<<dim3(D_ / 64, (B_ * S_) / 128), dim3(256), 0, stream>>>(Ob, wob, out);
}

// Round 6
// 159.299 us; speedup vs baseline: 1.0131x; 1.0131x over previous
//
#include <hip/hip_runtime.h>

typedef __attribute__((ext_vector_type(8))) short short8;
typedef __attribute__((ext_vector_type(4))) float f32x4;

#define MFMA(a,b,c) __builtin_amdgcn_mfma_f32_16x16x32_bf16((a),(b),(c),0,0,0)

#define B_  2
#define S_  2048
#define D_  1024
#define H_  16
#define DK  64
#define KDIM 1024

typedef unsigned int u32;
typedef __attribute__((address_space(1))) const u32 gu32;
typedef __attribute__((address_space(3))) u32 lu32;

// async global->LDS, 16 B per lane; LDS dest = base + lane*16 (wave-uniform base)
__device__ __forceinline__ void gll16(const unsigned short* g, unsigned short* l){
  __builtin_amdgcn_global_load_lds((gu32*)g, (lu32*)l, 16, 0, 0);
}

__device__ __forceinline__ unsigned short f2bf(float f){
  unsigned int u = __float_as_uint(f);
  u += 0x7fffu + ((u >> 16) & 1u);   // RNE (finite inputs only)
  return (unsigned short)(u >> 16);
}

// pack two f32 -> two bf16 (round-half-up) in 3 VALU: 2 adds + v_perm_b32.
__device__ __forceinline__ u32 pkbf(float lo, float hi){
  u32 a = __float_as_uint(lo) + 0x8000u;
  u32 b = __float_as_uint(hi) + 0x8000u;
  return __builtin_amdgcn_perm(b, a, 0x07060302u);
}

// ---------------- fp32 -> bf16 convert, all 5 tensors in one launch ---------
__global__ void cvt_all(const float* __restrict__ x,  const float* __restrict__ qw,
                        const float* __restrict__ kw, const float* __restrict__ vw,
                        const float* __restrict__ ow,
                        unsigned short* __restrict__ xb,  unsigned short* __restrict__ wqb,
                        unsigned short* __restrict__ wkb, unsigned short* __restrict__ wvb,
                        unsigned short* __restrict__ wob,
                        int n4x, int n4w){
  int i = blockIdx.x * 256 + threadIdx.x;
  const float* src; unsigned short* dst; int n4;
  switch (blockIdx.y) {
    case 0:  src = x;  dst = xb;  n4 = n4x; break;
    case 1:  src = qw; dst = wqb; n4 = n4w; break;
    case 2:  src = kw; dst = wkb; n4 = n4w; break;
    case 3:  src = vw; dst = wvb; n4 = n4w; break;
    default: src = ow; dst = wob; n4 = n4w; break;
  }
  if (i >= n4) return;
  float4 f = reinterpret_cast<const float4*>(src)[i];
  ushort4 u;
  u.x = f2bf(f.x); u.y = f2bf(f.y); u.z = f2bf(f.z); u.w = f2bf(f.w);
  reinterpret_cast<ushort4*>(dst)[i] = u;
}

// ---------------- FUSED QKV projection (one pass over X) --------------------
// One block computes the 128x64 output tile for ALL THREE projections:
// stages its X-tile ONCE + Wq/Wk/Wv tiles.  Per K-step per wave: 48 MFMA,
// 20 ds_read_b128, 10 global_load_lds.  LDS 80 KB -> 2 blocks/CU; grid 512.
// Chunk-XOR swizzle (conflict-free, verified R1) + depth-2 counted-vmcnt
// pipeline (verified R2): no vmcnt(0) drain in steady state.
struct FragsQKV { short8 a0[4], a1[4], b0[3][2], b1[3][2]; };

__global__ __launch_bounds__(256, 2) void gemm_qkv(
    const unsigned short* __restrict__ X,
    const unsigned short* __restrict__ Wq,
    const unsigned short* __restrict__ Wk,
    const unsigned short* __restrict__ Wv,
    unsigned short* __restrict__ Qo,
    unsigned short* __restrict__ Ko,
    unsigned short* __restrict__ Vo)
{
  const int n0 = blockIdx.x * 64;
  const int m0 = blockIdx.y * 128;

  __shared__ unsigned short As[2][128 * 64];      // 2 x 16 KiB
  __shared__ unsigned short Bs[2][3][64 * 64];    // 2 x 3 x 8 KiB

  const int tid  = threadIdx.x;
  const int wid  = tid >> 6, lane = tid & 63;
  const int wm   = (wid >> 1) * 64, wn = (wid & 1) * 32;
  const int lr   = lane & 15, c = lane >> 4;
  const int sw   = lr & 7;
  const int pc0  = (c ^ sw) * 8;               // k-half 0 chunk, shorts
  const int pc1  = ((c ^ 4) ^ sw) * 8;         // k-half 1 chunk, shorts

  const int srow = lane >> 3;                  // 0..7
  const int scol = ((lane & 7) ^ srow) * 8;    // inverse-swizzled source col
  const unsigned short* gA  = X  + (size_t)(m0 + wid * 32 + srow) * KDIM + scol;
  const unsigned short* gBq = Wq + (size_t)(n0 + wid * 16 + srow) * KDIM + scol;
  const unsigned short* gBk = Wk + (size_t)(n0 + wid * 16 + srow) * KDIM + scol;
  const unsigned short* gBv = Wv + (size_t)(n0 + wid * 16 + srow) * KDIM + scol;

  auto stage = [&](int buf, int k0) {
    unsigned short* la  = &As[buf][(wid * 32) * 64];
    unsigned short* lbq = &Bs[buf][0][(wid * 16) * 64];
    unsigned short* lbk = &Bs[buf][1][(wid * 16) * 64];
    unsigned short* lbv = &Bs[buf][2][(wid * 16) * 64];
#pragma unroll
    for (int i = 0; i < 4; i++) gll16(gA + (size_t)(i * 8) * KDIM + k0, la + i * 512);
#pragma unroll
    for (int i = 0; i < 2; i++) gll16(gBq + (size_t)(i * 8) * KDIM + k0, lbq + i * 512);
#pragma unroll
    for (int i = 0; i < 2; i++) gll16(gBk + (size_t)(i * 8) * KDIM + k0, lbk + i * 512);
#pragma unroll
    for (int i = 0; i < 2; i++) gll16(gBv + (size_t)(i * 8) * KDIM + k0, lbv + i * 512);
  };

  auto ldfr = [&](int buf, FragsQKV& f) {
    const unsigned short* AS = As[buf];
#pragma unroll
    for (int i = 0; i < 4; i++) {
      f.a0[i] = *(const short8*)&AS[(wm + i * 16 + lr) * 64 + pc0];
      f.a1[i] = *(const short8*)&AS[(wm + i * 16 + lr) * 64 + pc1];
    }
#pragma unroll
    for (int z = 0; z < 3; z++) {
      const unsigned short* BS = Bs[buf][z];
#pragma unroll
      for (int j = 0; j < 2; j++) {
        f.b0[z][j] = *(const short8*)&BS[(wn + j * 16 + lr) * 64 + pc0];
        f.b1[z][j] = *(const short8*)&BS[(wn + j * 16 + lr) * 64 + pc1];
      }
    }
  };

  f32x4 acc[3][4][2];
  const f32x4 z4 = {0.f, 0.f, 0.f, 0.f};
#pragma unroll
  for (int z = 0; z < 3; z++)
    for (int i = 0; i < 4; i++)
      for (int j = 0; j < 2; j++) acc[z][i][j] = z4;

  auto mfmas = [&](const FragsQKV& f) {
#pragma unroll
    for (int z = 0; z < 3; z++) {
      if (z == 2) {
#pragma unroll
        for (int i = 0; i < 4; i++)
#pragma unroll
          for (int j = 0; j < 2; j++) {
            acc[z][i][j] = MFMA(f.b0[z][j], f.a0[i], acc[z][i][j]);  // V: rows=W-dim
            acc[z][i][j] = MFMA(f.b1[z][j], f.a1[i], acc[z][i][j]);
          }
      } else {
#pragma unroll
        for (int i = 0; i < 4; i++)
#pragma unroll
          for (int j = 0; j < 2; j++) {
            acc[z][i][j] = MFMA(f.a0[i], f.b0[z][j], acc[z][i][j]);
            acc[z][i][j] = MFMA(f.a1[i], f.b1[z][j], acc[z][i][j]);
          }
      }
    }
  };

  // prologue: two tiles in flight (20 loads)
  stage(0, 0);
  stage(1, 64);

  FragsQKV f;
  const int NT = KDIM / 64;                    // 16
  for (int t = 0; t < NT - 2; ++t) {
    const int buf = t & 1;
    asm volatile("s_waitcnt vmcnt(10)" ::: "memory");  // my stage(t) landed
    __builtin_amdgcn_s_barrier();                       // everyone's landed
    asm volatile("" ::: "memory");
    ldfr(buf, f);
    asm volatile("s_waitcnt lgkmcnt(0)" ::: "memory"); // my reads serviced
    __builtin_amdgcn_sched_barrier(0);
    __builtin_amdgcn_s_barrier();                       // buf free to overwrite
    asm volatile("" ::: "memory");
    stage(buf, (t + 2) * 64);                           // 10 loads in flight
    __builtin_amdgcn_sched_barrier(0);
    mfmas(f);                                           // covers load latency
  }
  // t = NT-2: no further staging
  asm volatile("s_waitcnt vmcnt(10)" ::: "memory");
  __builtin_amdgcn_s_barrier();
  asm volatile("" ::: "memory");
  ldfr((NT - 2) & 1, f);
  mfmas(f);
  // t = NT-1: drain the last tile
  asm volatile("s_waitcnt vmcnt(0)" ::: "memory");
  __builtin_amdgcn_s_barrier();
  asm volatile("" ::: "memory");
  ldfr((NT - 1) & 1, f);
  mfmas(f);

  const int rbase = (lane >> 4) * 4;
  // z=0: Q (scaled), z=1: K, z=2: V^T
  for (int i = 0; i < 4; i++)
    for (int j = 0; j < 2; j++)
      for (int r = 0; r < 4; r++) {
        int m = m0 + wm + i * 16 + rbase + r;
        int n = n0 + wn + j * 16 + lr;
        int bb = m >> 11, s = m & 2047, h = n >> 6, d = n & 63;
        float vq = acc[0][i][j][r] * 0.18033688f;  // (1/sqrt(64))*log2(e)
        Qo[(((bb * H_ + h) * S_) + s) * DK + d] = f2bf(vq);
        Ko[(((bb * H_ + h) * S_) + s) * DK + d] = f2bf(acc[1][i][j][r]);
      }
  for (int i = 0; i < 4; i++)
    for (int j = 0; j < 2; j++)
      for (int r = 0; r < 4; r++) {
        int dfull = n0 + wn + j * 16 + rbase + r;   // W row (h,dk)
        int sfull = m0 + wm + i * 16 + lr;          // X row (b,s)
        int h = dfull >> 6, d = dfull & 63;
        int bb = sfull >> 11, s = sfull & 2047;
        Vo[(((bb * H_ + h) * DK) + d) * S_ + s] = f2bf(acc[2][i][j][r]);
      }
}

// ---------------- causal flash attention (R3 structure + XCD swizzle) -------
// Q,K: [B,H,S,DK] bf16 (Q pre-scaled to exp2 domain); V: [B,H,DK,S] bf16.
// R3 known-best config: 8 waves/512 thr, 16 q-rows per wave, ping-pong K/V
// buffers with 1 __syncthreads per tile, setprio around MFMA clusters,
// 50 KB LDS -> 3 blocks/CU = 24 waves (attn is latency-bound: R4/R5 showed
// occupancy is the lever, staging depth is not).
// NEW (T1): flat 512-block grid, XCD-aware swizzle — all 16 q-tiles of one
// (b,h) pair land on the same XCD (64 blocks/XCD = 4 pairs x 16 tiles), so
// K/V (512 KB/pair) becomes XCD-L2-resident instead of refetched per XCD.
// Causal balance kept: qt direction alternates by group so adjacent slots
// mix long/short blocks.
__global__ __launch_bounds__(512, 4) void attn(
    const unsigned short* __restrict__ Q,
    const unsigned short* __restrict__ K,
    const unsigned short* __restrict__ V,
    unsigned short* __restrict__ O)
{
  const int L    = blockIdx.x;                // 0..511
  const int xcd  = L & 7;
  const int slot = L >> 3;                    // 0..63
  const int g    = slot & 3;                  // group within XCD
  const int qi   = slot >> 2;                 // 0..15
  const int qt   = (g & 1) ? (15 - qi) : qi;  // balance causal work
  const int pair = xcd + 8 * g;               // 0..31
  const int b    = pair >> 4, h = pair & 15;

  const unsigned short* __restrict__ Qh = Q + (size_t)((b * H_ + h) * S_) * DK;
  const unsigned short* __restrict__ Kh = K + (size_t)((b * H_ + h) * S_) * DK;
  const unsigned short* __restrict__ Vh = V + (size_t)((b * H_ + h) * DK) * S_;

  __shared__ unsigned short Ks0[64 * 64];     // [key][d], swizzled chunks
  __shared__ unsigned short Ks1[64 * 64];
  __shared__ unsigned short Vs0[64 * 64];     // [d][key], swizzled chunks
  __shared__ unsigned short Vs1[64 * 64];
  __shared__ unsigned short Ps[8][16][72];    // per-wave: [q][key] (padded)

  const int tid = threadIdx.x, wid = tid >> 6, lane = tid & 63;
  const int lr = lane & 15;
  const int row4 = (lane >> 4) * 4;
  const int q0 = qt * 128;
  const int qcol = q0 + wid * 16 + lr;
  const int qwmin = q0 + wid * 16;
  const int qwmax = qwmin + 15;
  const int lk = (lane >> 4) * 8;             // for Q/P fragments (unswizzled)

  // swizzled LDS read offsets (shorts): logical chunk c=(lane>>4), rot by row
  const int pc0 = (((lane >> 4) + lr) & 7) * 8;
  const int pc1 = (((lane >> 4) + 4 + lr) & 7) * 8;

  // staging: wave wid covers rows [8*wid, 8*wid+8) of both K and V tiles
  const int sr8 = lane >> 3;                  // 0..7 row within chunk
  const int sc8 = lane & 7;                   // physical chunk
  const int sg  = (sc8 - sr8) & 7;            // logical chunk to fetch
  const int stRow = wid * 8 + sr8;            // 0..63
  const unsigned short* gK = Kh + (size_t)stRow * DK + sg * 8;
  const unsigned short* gV = Vh + (size_t)stRow * S_ + sg * 8;
  unsigned short* lK0 = &Ks0[wid * 8 * 64];
  unsigned short* lK1 = &Ks1[wid * 8 * 64];
  unsigned short* lV0 = &Vs0[wid * 8 * 64];
  unsigned short* lV1 = &Vs1[wid * 8 * 64];

  const short ONE = (short)0x3F80;            // bf16 1.0
  const short8 ones = {ONE, ONE, ONE, ONE, ONE, ONE, ONE, ONE};

  short8 qf[2];
  qf[0] = *(const short8*)&Qh[(q0 + wid * 16 + lr) * DK + lk];
  qf[1] = *(const short8*)&Qh[(q0 + wid * 16 + lr) * DK + 32 + lk];

  const f32x4 z4 = {0.f, 0.f, 0.f, 0.f};
  f32x4 o[4];
  for (int i = 0; i < 4; i++) o[i] = z4;
  f32x4 rs = z4;                              // l(q=lr) on the MFMA pipe

  auto tile = [&](int k0, const unsigned short* KS, const unsigned short* VS){
    if (k0 > qwmax) return;                   // wave-uniform skip
    f32x4 sc[4];
    __builtin_amdgcn_s_setprio(1);
    for (int nt = 0; nt < 4; nt++) {
      short8 kb0 = *(const short8*)&KS[(nt * 16 + lr) * 64 + pc0];
      short8 kb1 = *(const short8*)&KS[(nt * 16 + lr) * 64 + pc1];
      f32x4 s = MFMA(kb0, qf[0], z4);
      sc[nt] = MFMA(kb1, qf[1], s);
    }
    __builtin_amdgcn_s_setprio(0);
    if (k0 + 63 > qwmin) {                    // diagonal region: mask key > q
      for (int nt = 0; nt < 4; nt++) {
        int kg = k0 + nt * 16 + row4;
        for (int r = 0; r < 4; r++)
          if (kg + r > qcol) sc[nt][r] = -INFINITY;
      }
    }
    for (int nt = 0; nt < 4; nt++) {
      float p0 = __builtin_amdgcn_exp2f(sc[nt][0]);
      float p1 = __builtin_amdgcn_exp2f(sc[nt][1]);
      float p2 = __builtin_amdgcn_exp2f(sc[nt][2]);
      float p3 = __builtin_amdgcn_exp2f(sc[nt][3]);
      uint2 pk;
      pk.x = pkbf(p0, p1);
      pk.y = pkbf(p2, p3);
      *(uint2*)&Ps[wid][lr][nt * 16 + row4] = pk;
    }
    short8 pf0 = *(const short8*)&Ps[wid][lr][lk];
    short8 pf1 = *(const short8*)&Ps[wid][lr][32 + lk];
    __builtin_amdgcn_s_setprio(1);
    rs = MFMA(ones, pf0, rs);
    rs = MFMA(ones, pf1, rs);
    for (int dt = 0; dt < 4; dt++) {
      short8 vb0 = *(const short8*)&VS[(dt * 16 + lr) * 64 + pc0];
      short8 vb1 = *(const short8*)&VS[(dt * 16 + lr) * 64 + pc1];
      o[dt] = MFMA(vb0, pf0, o[dt]);
      o[dt] = MFMA(vb1, pf1, o[dt]);
    }
    __builtin_amdgcn_s_setprio(0);
  };

  const int kt_end = 2 * qt + 2;              // even

  // prologue: tile 0 into buf0
  gll16(gK, lK0);
  gll16(gV, lV0);

  for (int kt = 0; kt < kt_end; kt += 2) {
    const int k0 = kt * 64;
    __syncthreads();                          // buf0 (k0) ready
    {                                         // kt+1 always < kt_end
      gll16(gK + (size_t)(k0 + 64) * DK, lK1);
      gll16(gV + (k0 + 64),              lV1);
    }
    tile(k0, Ks0, Vs0);
    __syncthreads();                          // buf1 (k0+64) ready
    if (kt + 2 < kt_end) {
      gll16(gK + (size_t)(k0 + 128) * DK, lK0);
      gll16(gV + (k0 + 128),              lV0);
    }
    tile(k0 + 64, Ks1, Vs1);
  }

  const float inv = 1.0f / rs[0];

  const int srow = q0 + wid * 16 + lr;
  for (int dt = 0; dt < 4; dt++) {
    uint2 pk;
    pk.x = pkbf(o[dt][0] * inv, o[dt][1] * inv);
    pk.y = pkbf(o[dt][2] * inv, o[dt][3] * inv);
    *(uint2*)&O[(size_t)(b * S_ + srow) * D_ + h * DK + dt * 16 + row4] = pk;
  }
}

struct Frags { short8 a0[4], a1[4], b0[2], b1[2]; };

// ---------------- output projection (counted-vmcnt pipeline, fp32 out) ------
__global__ __launch_bounds__(256) void gemm_oproj(
    const unsigned short* __restrict__ A,
    const unsigned short* __restrict__ W,
    float* __restrict__ out)
{
  const int n0 = blockIdx.x * 64;
  const int m0 = blockIdx.y * 128;

  __shared__ unsigned short As[2][128 * 64];
  __shared__ unsigned short Bs[2][64 * 64];

  const int tid  = threadIdx.x;
  const int wid  = tid >> 6, lane = tid & 63;
  const int wm   = (wid >> 1) * 64, wn = (wid & 1) * 32;
  const int lr   = lane & 15, c = lane >> 4;
  const int sw   = lr & 7;
  const int pc0  = (c ^ sw) * 8;
  const int pc1  = ((c ^ 4) ^ sw) * 8;

  const int srow = lane >> 3;
  const int scol = ((lane & 7) ^ srow) * 8;
  const unsigned short* gA = A + (size_t)(m0 + wid * 32 + srow) * KDIM + scol;
  const unsigned short* gB = W + (size_t)(n0 + wid * 16 + srow) * KDIM + scol;

  auto stage = [&](int buf, int k0) {
    unsigned short* la = &As[buf][(wid * 32) * 64];
    unsigned short* lb = &Bs[buf][(wid * 16) * 64];
#pragma unroll
    for (int i = 0; i < 4; i++) gll16(gA + (size_t)(i * 8) * KDIM + k0, la + i * 512);
#pragma unroll
    for (int i = 0; i < 2; i++) gll16(gB + (size_t)(i * 8) * KDIM + k0, lb + i * 512);
  };

  auto ldfr = [&](int buf, Frags& f) {
    const unsigned short* AS = As[buf];
    const unsigned short* BS = Bs[buf];
#pragma unroll
    for (int i = 0; i < 4; i++) {
      f.a0[i] = *(const short8*)&AS[(wm + i * 16 + lr) * 64 + pc0];
      f.a1[i] = *(const short8*)&AS[(wm + i * 16 + lr) * 64 + pc1];
    }
#pragma unroll
    for (int j = 0; j < 2; j++) {
      f.b0[j] = *(const short8*)&BS[(wn + j * 16 + lr) * 64 + pc0];
      f.b1[j] = *(const short8*)&BS[(wn + j * 16 + lr) * 64 + pc1];
    }
  };

  f32x4 acc[4][2];
  const f32x4 z4 = {0.f, 0.f, 0.f, 0.f};
  for (int i = 0; i < 4; i++)
    for (int j = 0; j < 2; j++) acc[i][j] = z4;

  auto mfmas = [&](const Frags& f) {
#pragma unroll
    for (int i = 0; i < 4; i++)
#pragma unroll
      for (int j = 0; j < 2; j++) {
        acc[i][j] = MFMA(f.a0[i], f.b0[j], acc[i][j]);
        acc[i][j] = MFMA(f.a1[i], f.b1[j], acc[i][j]);
      }
  };

  stage(0, 0);
  stage(1, 64);

  Frags f;
  const int NT = KDIM / 64;                    // 16
  for (int t = 0; t < NT - 2; ++t) {
    const int buf = t & 1;
    asm volatile("s_waitcnt vmcnt(6)" ::: "memory");
    __builtin_amdgcn_s_barrier();
    asm volatile("" ::: "memory");
    ldfr(buf, f);
    asm volatile("s_waitcnt lgkmcnt(0)" ::: "memory");
    __builtin_amdgcn_sched_barrier(0);
    __builtin_amdgcn_s_barrier();
    asm volatile("" ::: "memory");
    stage(buf, (t + 2) * 64);
    __builtin_amdgcn_sched_barrier(0);
    mfmas(f);
  }
  asm volatile("s_waitcnt vmcnt(6)" ::: "memory");
  __builtin_amdgcn_s_barrier();
  asm volatile("" ::: "memory");
  ldfr((NT - 2) & 1, f);
  mfmas(f);
  asm volatile("s_waitcnt vmcnt(0)" ::: "memory");
  __builtin_amdgcn_s_barrier();
  asm volatile("" ::: "memory");
  ldfr((NT - 1) & 1, f);
  mfmas(f);

  const int rbase = (lane >> 4) * 4;
  for (int i = 0; i < 4; i++)
    for (int j = 0; j < 2; j++)
      for (int r = 0; r < 4; r++) {
        int m = m0 + wm + i * 16 + rbase + r;
        int n = n0 + wn + j * 16 + lr;
        out[(size_t)m * D_ + n] = acc[i][j][r];
      }
}

extern "C" void kernel_launch(void* const* d_in, const int* in_sizes, int n_in,
                              void* d_out, int out_size, void* d_ws, size_t ws_size,
                              hipStream_t stream) {
  const float* x  = (const float*)d_in[0];
  const float* qw = (const float*)d_in[1];
  const float* kw = (const float*)d_in[2];
  const float* vw = (const float*)d_in[3];
  const float* ow = (const float*)d_in[4];
  float* out = (float*)d_out;

  char* ws = (char*)d_ws;
  size_t off = 0;
  auto alloc = [&](size_t bytes) -> void* {
    void* p = ws + off;
    off += (bytes + 255) & ~(size_t)255;
    return p;
  };
  const size_t XN = (size_t)B_ * S_ * D_;     // 4194304
  const size_t WN = (size_t)D_ * D_;          // 1048576
  unsigned short* xb  = (unsigned short*)alloc(XN * 2);
  unsigned short* wqb = (unsigned short*)alloc(WN * 2);
  unsigned short* wkb = (unsigned short*)alloc(WN * 2);
  unsigned short* wvb = (unsigned short*)alloc(WN * 2);
  unsigned short* wob = (unsigned short*)alloc(WN * 2);
  unsigned short* Qb  = (unsigned short*)alloc(XN * 2);
  unsigned short* Kb  = (unsigned short*)alloc(XN * 2);
  unsigned short* Vb  = (unsigned short*)alloc(XN * 2);
  unsigned short* Ob  = (unsigned short*)alloc(XN * 2);

  cvt_all<<<dim3((XN / 4 + 255) / 256, 5), dim3(256), 0, stream>>>(
      x, qw, kw, vw, ow, xb, wqb, wkb, wvb, wob, (int)(XN / 4), (int)(WN / 4));

  gemm_qkv<<<dim3(D_ / 64, (B_ * S_) / 128), dim3(256), 0, stream>>>(
      xb, wqb, wkb, wvb, Qb, Kb, Vb);

  attn<<<dim3(512, 1, 1), dim3(512), 0, stream>>>(Qb, Kb, Vb, Ob);

  gemm_oproj<<<dim3(D_ / 64, (B_ * S_) / 128), dim3(256), 0, stream>>>(Ob, wob, out);
}

// Round 7
// 156.817 us; speedup vs baseline: 1.0291x; 1.0158x over previous
//
#include <hip/hip_runtime.h>

typedef __attribute__((ext_vector_type(8))) short short8;
typedef __attribute__((ext_vector_type(4))) float f32x4;

#define MFMA(a,b,c) __builtin_amdgcn_mfma_f32_16x16x32_bf16((a),(b),(c),0,0,0)

#define B_  2
#define S_  2048
#define D_  1024
#define H_  16
#define DK  64
#define KDIM 1024

typedef unsigned int u32;
typedef __attribute__((address_space(1))) const u32 gu32;
typedef __attribute__((address_space(3))) u32 lu32;

// async global->LDS, 16 B per lane; LDS dest = base + lane*16 (wave-uniform base)
__device__ __forceinline__ void gll16(const unsigned short* g, unsigned short* l){
  __builtin_amdgcn_global_load_lds((gu32*)g, (lu32*)l, 16, 0, 0);
}

__device__ __forceinline__ unsigned short f2bf(float f){
  unsigned int u = __float_as_uint(f);
  u += 0x7fffu + ((u >> 16) & 1u);   // RNE (finite inputs only)
  return (unsigned short)(u >> 16);
}

// pack two f32 -> two bf16 (round-half-up) in 3 VALU: 2 adds + v_perm_b32.
__device__ __forceinline__ u32 pkbf(float lo, float hi){
  u32 a = __float_as_uint(lo) + 0x8000u;
  u32 b = __float_as_uint(hi) + 0x8000u;
  return __builtin_amdgcn_perm(b, a, 0x07060302u);
}

// ---------------- fp32 -> bf16 convert, all 5 tensors in one launch ---------
__global__ void cvt_all(const float* __restrict__ x,  const float* __restrict__ qw,
                        const float* __restrict__ kw, const float* __restrict__ vw,
                        const float* __restrict__ ow,
                        unsigned short* __restrict__ xb,  unsigned short* __restrict__ wqb,
                        unsigned short* __restrict__ wkb, unsigned short* __restrict__ wvb,
                        unsigned short* __restrict__ wob,
                        int n4x, int n4w){
  int i = blockIdx.x * 256 + threadIdx.x;
  const float* src; unsigned short* dst; int n4;
  switch (blockIdx.y) {
    case 0:  src = x;  dst = xb;  n4 = n4x; break;
    case 1:  src = qw; dst = wqb; n4 = n4w; break;
    case 2:  src = kw; dst = wkb; n4 = n4w; break;
    case 3:  src = vw; dst = wvb; n4 = n4w; break;
    default: src = ow; dst = wob; n4 = n4w; break;
  }
  if (i >= n4) return;
  float4 f = reinterpret_cast<const float4*>(src)[i];
  ushort4 u;
  u.x = f2bf(f.x); u.y = f2bf(f.y); u.z = f2bf(f.z); u.w = f2bf(f.w);
  reinterpret_cast<ushort4*>(dst)[i] = u;
}

// ---------------- FUSED QKV projection (one pass over X) --------------------
// One block computes the 128x64 output tile for ALL THREE projections:
// stages its X-tile ONCE + Wq/Wk/Wv tiles.  Per K-step per wave: 48 MFMA,
// 20 ds_read_b128, 10 global_load_lds.  LDS 80 KB -> 2 blocks/CU; grid 512.
// Chunk-XOR swizzle (conflict-free, verified R1) + depth-2 counted-vmcnt
// pipeline (verified R2): no vmcnt(0) drain in steady state.
// R7: per-tensor MFMA operand order chosen so each thread's 4 acc regs span
// 4 CONSECUTIVE memory elements -> uint2-packed epilogue stores (8 B/lane,
// 4x fewer store insts).  Q/K swapped (reg->d, lane->s); V normal (reg->s,
// lane->d).  Mapping identical to the V path verified since R0.
struct FragsQKV { short8 a0[4], a1[4], b0[3][2], b1[3][2]; };

__global__ __launch_bounds__(256, 2) void gemm_qkv(
    const unsigned short* __restrict__ X,
    const unsigned short* __restrict__ Wq,
    const unsigned short* __restrict__ Wk,
    const unsigned short* __restrict__ Wv,
    unsigned short* __restrict__ Qo,
    unsigned short* __restrict__ Ko,
    unsigned short* __restrict__ Vo)
{
  const int n0 = blockIdx.x * 64;
  const int m0 = blockIdx.y * 128;

  __shared__ unsigned short As[2][128 * 64];      // 2 x 16 KiB
  __shared__ unsigned short Bs[2][3][64 * 64];    // 2 x 3 x 8 KiB

  const int tid  = threadIdx.x;
  const int wid  = tid >> 6, lane = tid & 63;
  const int wm   = (wid >> 1) * 64, wn = (wid & 1) * 32;
  const int lr   = lane & 15, c = lane >> 4;
  const int sw   = lr & 7;
  const int pc0  = (c ^ sw) * 8;               // k-half 0 chunk, shorts
  const int pc1  = ((c ^ 4) ^ sw) * 8;         // k-half 1 chunk, shorts

  const int srow = lane >> 3;                  // 0..7
  const int scol = ((lane & 7) ^ srow) * 8;    // inverse-swizzled source col
  const unsigned short* gA  = X  + (size_t)(m0 + wid * 32 + srow) * KDIM + scol;
  const unsigned short* gBq = Wq + (size_t)(n0 + wid * 16 + srow) * KDIM + scol;
  const unsigned short* gBk = Wk + (size_t)(n0 + wid * 16 + srow) * KDIM + scol;
  const unsigned short* gBv = Wv + (size_t)(n0 + wid * 16 + srow) * KDIM + scol;

  auto stage = [&](int buf, int k0) {
    unsigned short* la  = &As[buf][(wid * 32) * 64];
    unsigned short* lbq = &Bs[buf][0][(wid * 16) * 64];
    unsigned short* lbk = &Bs[buf][1][(wid * 16) * 64];
    unsigned short* lbv = &Bs[buf][2][(wid * 16) * 64];
#pragma unroll
    for (int i = 0; i < 4; i++) gll16(gA + (size_t)(i * 8) * KDIM + k0, la + i * 512);
#pragma unroll
    for (int i = 0; i < 2; i++) gll16(gBq + (size_t)(i * 8) * KDIM + k0, lbq + i * 512);
#pragma unroll
    for (int i = 0; i < 2; i++) gll16(gBk + (size_t)(i * 8) * KDIM + k0, lbk + i * 512);
#pragma unroll
    for (int i = 0; i < 2; i++) gll16(gBv + (size_t)(i * 8) * KDIM + k0, lbv + i * 512);
  };

  auto ldfr = [&](int buf, FragsQKV& f) {
    const unsigned short* AS = As[buf];
#pragma unroll
    for (int i = 0; i < 4; i++) {
      f.a0[i] = *(const short8*)&AS[(wm + i * 16 + lr) * 64 + pc0];
      f.a1[i] = *(const short8*)&AS[(wm + i * 16 + lr) * 64 + pc1];
    }
#pragma unroll
    for (int z = 0; z < 3; z++) {
      const unsigned short* BS = Bs[buf][z];
#pragma unroll
      for (int j = 0; j < 2; j++) {
        f.b0[z][j] = *(const short8*)&BS[(wn + j * 16 + lr) * 64 + pc0];
        f.b1[z][j] = *(const short8*)&BS[(wn + j * 16 + lr) * 64 + pc1];
      }
    }
  };

  f32x4 acc[3][4][2];
  const f32x4 z4 = {0.f, 0.f, 0.f, 0.f};
#pragma unroll
  for (int z = 0; z < 3; z++)
    for (int i = 0; i < 4; i++)
      for (int j = 0; j < 2; j++) acc[z][i][j] = z4;

  auto mfmas = [&](const FragsQKV& f) {
#pragma unroll
    for (int z = 0; z < 3; z++) {
      if (z < 2) {                 // Q,K swapped: acc reg -> W-row (h,d)
#pragma unroll
        for (int i = 0; i < 4; i++)
#pragma unroll
          for (int j = 0; j < 2; j++) {
            acc[z][i][j] = MFMA(f.b0[z][j], f.a0[i], acc[z][i][j]);
            acc[z][i][j] = MFMA(f.b1[z][j], f.a1[i], acc[z][i][j]);
          }
      } else {                     // V normal: acc reg -> X-row (b,s)
#pragma unroll
        for (int i = 0; i < 4; i++)
#pragma unroll
          for (int j = 0; j < 2; j++) {
            acc[z][i][j] = MFMA(f.a0[i], f.b0[z][j], acc[z][i][j]);
            acc[z][i][j] = MFMA(f.a1[i], f.b1[z][j], acc[z][i][j]);
          }
      }
    }
  };

  // prologue: two tiles in flight (20 loads)
  stage(0, 0);
  stage(1, 64);

  FragsQKV f;
  const int NT = KDIM / 64;                    // 16
  for (int t = 0; t < NT - 2; ++t) {
    const int buf = t & 1;
    asm volatile("s_waitcnt vmcnt(10)" ::: "memory");  // my stage(t) landed
    __builtin_amdgcn_s_barrier();                       // everyone's landed
    asm volatile("" ::: "memory");
    ldfr(buf, f);
    asm volatile("s_waitcnt lgkmcnt(0)" ::: "memory"); // my reads serviced
    __builtin_amdgcn_sched_barrier(0);
    __builtin_amdgcn_s_barrier();                       // buf free to overwrite
    asm volatile("" ::: "memory");
    stage(buf, (t + 2) * 64);                           // 10 loads in flight
    __builtin_amdgcn_sched_barrier(0);
    mfmas(f);                                           // covers load latency
  }
  // t = NT-2: no further staging
  asm volatile("s_waitcnt vmcnt(10)" ::: "memory");
  __builtin_amdgcn_s_barrier();
  asm volatile("" ::: "memory");
  ldfr((NT - 2) & 1, f);
  mfmas(f);
  // t = NT-1: drain the last tile
  asm volatile("s_waitcnt vmcnt(0)" ::: "memory");
  __builtin_amdgcn_s_barrier();
  asm volatile("" ::: "memory");
  ldfr((NT - 1) & 1, f);
  mfmas(f);

  const int rbase = (lane >> 4) * 4;
  // Q,K (swapped): reg r -> d (4 consecutive), lane -> (b,s).  uint2 stores.
#pragma unroll
  for (int i = 0; i < 4; i++) {
    const int m = m0 + wm + i * 16 + lr;       // X row
    const int bb = m >> 11, s = m & 2047;
#pragma unroll
    for (int j = 0; j < 2; j++) {
      const int nb = n0 + wn + j * 16 + rbase; // W row base: 4 consecutive d
      const int h = nb >> 6, d = nb & 63;
      const size_t off = ((size_t)(bb * H_ + h) * S_ + s) * DK + d;
      uint2 pq, pk;
      pq.x = pkbf(acc[0][i][j][0] * 0.18033688f, acc[0][i][j][1] * 0.18033688f);
      pq.y = pkbf(acc[0][i][j][2] * 0.18033688f, acc[0][i][j][3] * 0.18033688f);
      pk.x = pkbf(acc[1][i][j][0], acc[1][i][j][1]);
      pk.y = pkbf(acc[1][i][j][2], acc[1][i][j][3]);
      *(uint2*)&Qo[off] = pq;                  // (1/sqrt(64))*log2(e) folded
      *(uint2*)&Ko[off] = pk;
    }
  }
  // V (normal): reg r -> s (4 consecutive), lane -> (h,d).  V^T layout.
#pragma unroll
  for (int i = 0; i < 4; i++) {
    const int mb = m0 + wm + i * 16 + rbase;   // X row base: 4 consecutive s
    const int bb = mb >> 11, s = mb & 2047;
#pragma unroll
    for (int j = 0; j < 2; j++) {
      const int n = n0 + wn + j * 16 + lr;     // W row
      const int h = n >> 6, d = n & 63;
      uint2 pv;
      pv.x = pkbf(acc[2][i][j][0], acc[2][i][j][1]);
      pv.y = pkbf(acc[2][i][j][2], acc[2][i][j][3]);
      *(uint2*)&Vo[((size_t)(bb * H_ + h) * DK + d) * S_ + s] = pv;
    }
  }
}

// ---------------- causal flash attention (R3 exact: known best) -------------
// Q,K: [B,H,S,DK] bf16 (Q pre-scaled to exp2 domain); V: [B,H,DK,S] bf16.
// 8 waves/512 thr, 16 q-rows per wave, ping-pong K/V buffers, 1 barrier per
// tile, setprio around MFMA clusters.  50 KB LDS.  3D grid with causal
// pairing qt = b ? 15-x : x (XCD swizzle measured -6.7 us in R6: dropped).
__global__ __launch_bounds__(512, 4) void attn(
    const unsigned short* __restrict__ Q,
    const unsigned short* __restrict__ K,
    const unsigned short* __restrict__ V,
    unsigned short* __restrict__ O)
{
  const int h = blockIdx.y, b = blockIdx.z;
  const int qt = b ? (15 - blockIdx.x) : blockIdx.x;

  const unsigned short* __restrict__ Qh = Q + (size_t)((b * H_ + h) * S_) * DK;
  const unsigned short* __restrict__ Kh = K + (size_t)((b * H_ + h) * S_) * DK;
  const unsigned short* __restrict__ Vh = V + (size_t)((b * H_ + h) * DK) * S_;

  __shared__ unsigned short Ks0[64 * 64];     // [key][d], swizzled chunks
  __shared__ unsigned short Ks1[64 * 64];
  __shared__ unsigned short Vs0[64 * 64];     // [d][key], swizzled chunks
  __shared__ unsigned short Vs1[64 * 64];
  __shared__ unsigned short Ps[8][16][72];    // per-wave: [q][key] (padded)

  const int tid = threadIdx.x, wid = tid >> 6, lane = tid & 63;
  const int lr = lane & 15;
  const int row4 = (lane >> 4) * 4;
  const int q0 = qt * 128;
  const int qcol = q0 + wid * 16 + lr;
  const int qwmin = q0 + wid * 16;
  const int qwmax = qwmin + 15;
  const int lk = (lane >> 4) * 8;             // for Q/P fragments (unswizzled)

  // swizzled LDS read offsets (shorts): logical chunk c=(lane>>4), rot by row
  const int pc0 = (((lane >> 4) + lr) & 7) * 8;
  const int pc1 = (((lane >> 4) + 4 + lr) & 7) * 8;

  // staging: wave wid covers rows [8*wid, 8*wid+8) of both K and V tiles
  const int sr8 = lane >> 3;                  // 0..7 row within chunk
  const int sc8 = lane & 7;                   // physical chunk
  const int sg  = (sc8 - sr8) & 7;            // logical chunk to fetch
  const int stRow = wid * 8 + sr8;            // 0..63
  const unsigned short* gK = Kh + (size_t)stRow * DK + sg * 8;
  const unsigned short* gV = Vh + (size_t)stRow * S_ + sg * 8;
  unsigned short* lK0 = &Ks0[wid * 8 * 64];
  unsigned short* lK1 = &Ks1[wid * 8 * 64];
  unsigned short* lV0 = &Vs0[wid * 8 * 64];
  unsigned short* lV1 = &Vs1[wid * 8 * 64];

  const short ONE = (short)0x3F80;            // bf16 1.0
  const short8 ones = {ONE, ONE, ONE, ONE, ONE, ONE, ONE, ONE};

  short8 qf[2];
  qf[0] = *(const short8*)&Qh[(q0 + wid * 16 + lr) * DK + lk];
  qf[1] = *(const short8*)&Qh[(q0 + wid * 16 + lr) * DK + 32 + lk];

  const f32x4 z4 = {0.f, 0.f, 0.f, 0.f};
  f32x4 o[4];
  for (int i = 0; i < 4; i++) o[i] = z4;
  f32x4 rs = z4;                              // l(q=lr) on the MFMA pipe

  auto tile = [&](int k0, const unsigned short* KS, const unsigned short* VS){
    if (k0 > qwmax) return;                   // wave-uniform skip
    f32x4 sc[4];
    __builtin_amdgcn_s_setprio(1);
    for (int nt = 0; nt < 4; nt++) {
      short8 kb0 = *(const short8*)&KS[(nt * 16 + lr) * 64 + pc0];
      short8 kb1 = *(const short8*)&KS[(nt * 16 + lr) * 64 + pc1];
      f32x4 s = MFMA(kb0, qf[0], z4);
      sc[nt] = MFMA(kb1, qf[1], s);
    }
    __builtin_amdgcn_s_setprio(0);
    if (k0 + 63 > qwmin) {                    // diagonal region: mask key > q
      for (int nt = 0; nt < 4; nt++) {
        int kg = k0 + nt * 16 + row4;
        for (int r = 0; r < 4; r++)
          if (kg + r > qcol) sc[nt][r] = -INFINITY;
      }
    }
    for (int nt = 0; nt < 4; nt++) {
      float p0 = __builtin_amdgcn_exp2f(sc[nt][0]);
      float p1 = __builtin_amdgcn_exp2f(sc[nt][1]);
      float p2 = __builtin_amdgcn_exp2f(sc[nt][2]);
      float p3 = __builtin_amdgcn_exp2f(sc[nt][3]);
      uint2 pk;
      pk.x = pkbf(p0, p1);
      pk.y = pkbf(p2, p3);
      *(uint2*)&Ps[wid][lr][nt * 16 + row4] = pk;
    }
    short8 pf0 = *(const short8*)&Ps[wid][lr][lk];
    short8 pf1 = *(const short8*)&Ps[wid][lr][32 + lk];
    __builtin_amdgcn_s_setprio(1);
    rs = MFMA(ones, pf0, rs);
    rs = MFMA(ones, pf1, rs);
    for (int dt = 0; dt < 4; dt++) {
      short8 vb0 = *(const short8*)&VS[(dt * 16 + lr) * 64 + pc0];
      short8 vb1 = *(const short8*)&VS[(dt * 16 + lr) * 64 + pc1];
      o[dt] = MFMA(vb0, pf0, o[dt]);
      o[dt] = MFMA(vb1, pf1, o[dt]);
    }
    __builtin_amdgcn_s_setprio(0);
  };

  const int kt_end = 2 * qt + 2;              // even

  // prologue: tile 0 into buf0
  gll16(gK, lK0);
  gll16(gV, lV0);

  for (int kt = 0; kt < kt_end; kt += 2) {
    const int k0 = kt * 64;
    __syncthreads();                          // buf0 (k0) ready
    {                                         // kt+1 always < kt_end
      gll16(gK + (size_t)(k0 + 64) * DK, lK1);
      gll16(gV + (k0 + 64),              lV1);
    }
    tile(k0, Ks0, Vs0);
    __syncthreads();                          // buf1 (k0+64) ready
    if (kt + 2 < kt_end) {
      gll16(gK + (size_t)(k0 + 128) * DK, lK0);
      gll16(gV + (k0 + 128),              lV0);
    }
    tile(k0 + 64, Ks1, Vs1);
  }

  const float inv = 1.0f / rs[0];

  const int srow = q0 + wid * 16 + lr;
  for (int dt = 0; dt < 4; dt++) {
    uint2 pk;
    pk.x = pkbf(o[dt][0] * inv, o[dt][1] * inv);
    pk.y = pkbf(o[dt][2] * inv, o[dt][3] * inv);
    *(uint2*)&O[(size_t)(b * S_ + srow) * D_ + h * DK + dt * 16 + row4] = pk;
  }
}

struct Frags { short8 a0[4], a1[4], b0[2], b1[2]; };

// ---------------- output projection (counted-vmcnt pipeline, fp32 out) ------
__global__ __launch_bounds__(256) void gemm_oproj(
    const unsigned short* __restrict__ A,
    const unsigned short* __restrict__ W,
    float* __restrict__ out)
{
  const int n0 = blockIdx.x * 64;
  const int m0 = blockIdx.y * 128;

  __shared__ unsigned short As[2][128 * 64];
  __shared__ unsigned short Bs[2][64 * 64];

  const int tid  = threadIdx.x;
  const int wid  = tid >> 6, lane = tid & 63;
  const int wm   = (wid >> 1) * 64, wn = (wid & 1) * 32;
  const int lr   = lane & 15, c = lane >> 4;
  const int sw   = lr & 7;
  const int pc0  = (c ^ sw) * 8;
  const int pc1  = ((c ^ 4) ^ sw) * 8;

  const int srow = lane >> 3;
  const int scol = ((lane & 7) ^ srow) * 8;
  const unsigned short* gA = A + (size_t)(m0 + wid * 32 + srow) * KDIM + scol;
  const unsigned short* gB = W + (size_t)(n0 + wid * 16 + srow) * KDIM + scol;

  auto stage = [&](int buf, int k0) {
    unsigned short* la = &As[buf][(wid * 32) * 64];
    unsigned short* lb = &Bs[buf][(wid * 16) * 64];
#pragma unroll
    for (int i = 0; i < 4; i++) gll16(gA + (size_t)(i * 8) * KDIM + k0, la + i * 512);
#pragma unroll
    for (int i = 0; i < 2; i++) gll16(gB + (size_t)(i * 8) * KDIM + k0, lb + i * 512);
  };

  auto ldfr = [&](int buf, Frags& f) {
    const unsigned short* AS = As[buf];
    const unsigned short* BS = Bs[buf];
#pragma unroll
    for (int i = 0; i < 4; i++) {
      f.a0[i] = *(const short8*)&AS[(wm + i * 16 + lr) * 64 + pc0];
      f.a1[i] = *(const short8*)&AS[(wm + i * 16 + lr) * 64 + pc1];
    }
#pragma unroll
    for (int j = 0; j < 2; j++) {
      f.b0[j] = *(const short8*)&BS[(wn + j * 16 + lr) * 64 + pc0];
      f.b1[j] = *(const short8*)&BS[(wn + j * 16 + lr) * 64 + pc1];
    }
  };

  f32x4 acc[4][2];
  const f32x4 z4 = {0.f, 0.f, 0.f, 0.f};
  for (int i = 0; i < 4; i++)
    for (int j = 0; j < 2; j++) acc[i][j] = z4;

  auto mfmas = [&](const Frags& f) {
#pragma unroll
    for (int i = 0; i < 4; i++)
#pragma unroll
      for (int j = 0; j < 2; j++) {
        acc[i][j] = MFMA(f.a0[i], f.b0[j], acc[i][j]);
        acc[i][j] = MFMA(f.a1[i], f.b1[j], acc[i][j]);
      }
  };

  stage(0, 0);
  stage(1, 64);

  Frags f;
  const int NT = KDIM / 64;                    // 16
  for (int t = 0; t < NT - 2; ++t) {
    const int buf = t & 1;
    asm volatile("s_waitcnt vmcnt(6)" ::: "memory");
    __builtin_amdgcn_s_barrier();
    asm volatile("" ::: "memory");
    ldfr(buf, f);
    asm volatile("s_waitcnt lgkmcnt(0)" ::: "memory");
    __builtin_amdgcn_sched_barrier(0);
    __builtin_amdgcn_s_barrier();
    asm volatile("" ::: "memory");
    stage(buf, (t + 2) * 64);
    __builtin_amdgcn_sched_barrier(0);
    mfmas(f);
  }
  asm volatile("s_waitcnt vmcnt(6)" ::: "memory");
  __builtin_amdgcn_s_barrier();
  asm volatile("" ::: "memory");
  ldfr((NT - 2) & 1, f);
  mfmas(f);
  asm volatile("s_waitcnt vmcnt(0)" ::: "memory");
  __builtin_amdgcn_s_barrier();
  asm volatile("" ::: "memory");
  ldfr((NT - 1) & 1, f);
  mfmas(f);

  const int rbase = (lane >> 4) * 4;
  for (int i = 0; i < 4; i++)
    for (int j = 0; j < 2; j++)
      for (int r = 0; r < 4; r++) {
        int m = m0 + wm + i * 16 + rbase + r;
        int n = n0 + wn + j * 16 + lr;
        out[(size_t)m * D_ + n] = acc[i][j][r];
      }
}

extern "C" void kernel_launch(void* const* d_in, const int* in_sizes, int n_in,
                              void* d_out, int out_size, void* d_ws, size_t ws_size,
                              hipStream_t stream) {
  const float* x  = (const float*)d_in[0];
  const float* qw = (const float*)d_in[1];
  const float* kw = (const float*)d_in[2];
  const float* vw = (const float*)d_in[3];
  const float* ow = (const float*)d_in[4];
  float* out = (float*)d_out;

  char* ws = (char*)d_ws;
  size_t off = 0;
  auto alloc = [&](size_t bytes) -> void* {
    void* p = ws + off;
    off += (bytes + 255) & ~(size_t)255;
    return p;
  };
  const size_t XN = (size_t)B_ * S_ * D_;     // 4194304
  const size_t WN = (size_t)D_ * D_;          // 1048576
  unsigned short* xb  = (unsigned short*)alloc(XN * 2);
  unsigned short* wqb = (unsigned short*)alloc(WN * 2);
  unsigned short* wkb = (unsigned short*)alloc(WN * 2);
  unsigned short* wvb = (unsigned short*)alloc(WN * 2);
  unsigned short* wob = (unsigned short*)alloc(WN * 2);
  unsigned short* Qb  = (unsigned short*)alloc(XN * 2);
  unsigned short* Kb  = (unsigned short*)alloc(XN * 2);
  unsigned short* Vb  = (unsigned short*)alloc(XN * 2);
  unsigned short* Ob  = (unsigned short*)alloc(XN * 2);

  cvt_all<<<dim3((XN / 4 + 255) / 256, 5), dim3(256), 0, stream>>>(
      x, qw, kw, vw, ow, xb, wqb, wkb, wvb, wob, (int)(XN / 4), (int)(WN / 4));

  gemm_qkv<<<dim3(D_ / 64, (B_ * S_) / 128), dim3(256), 0, stream>>>(
      xb, wqb, wkb, wvb, Qb, Kb, Vb);

  attn<<<dim3(S_ / 128, H_, B_), dim3(512), 0, stream>>>(Qb, Kb, Vb, Ob);

  gemm_oproj<<<dim3(D_ / 64, (B_ * S_) / 128), dim3(256), 0, stream>>>(Ob, wob, out);
}

// Round 8
// 154.193 us; speedup vs baseline: 1.0466x; 1.0170x over previous
//
#include <hip/hip_runtime.h>

typedef __attribute__((ext_vector_type(8))) short short8;
typedef __attribute__((ext_vector_type(4))) float f32x4;
typedef __attribute__((ext_vector_type(4))) unsigned int u32x4;

#define MFMA(a,b,c) __builtin_amdgcn_mfma_f32_16x16x32_bf16((a),(b),(c),0,0,0)

#define B_  2
#define S_  2048
#define D_  1024
#define H_  16
#define DK  64
#define KDIM 1024

typedef unsigned int u32;
typedef __attribute__((address_space(1))) const u32 gu32;
typedef __attribute__((address_space(3))) u32 lu32;

// async global->LDS, 16 B per lane; LDS dest = base + lane*16 (wave-uniform base)
__device__ __forceinline__ void gll16(const unsigned short* g, unsigned short* l){
  __builtin_amdgcn_global_load_lds((gu32*)g, (lu32*)l, 16, 0, 0);
}

__device__ __forceinline__ unsigned short f2bf(float f){
  unsigned int u = __float_as_uint(f);
  u += 0x7fffu + ((u >> 16) & 1u);   // RNE (finite inputs only)
  return (unsigned short)(u >> 16);
}

// pack two f32 -> two bf16 (round-half-up) in 3 VALU: 2 adds + v_perm_b32.
__device__ __forceinline__ u32 pkbf(float lo, float hi){
  u32 a = __float_as_uint(lo) + 0x8000u;
  u32 b = __float_as_uint(hi) + 0x8000u;
  return __builtin_amdgcn_perm(b, a, 0x07060302u);
}

// ---------------- fp32 -> bf16 convert, all 5 tensors in one launch ---------
__global__ void cvt_all(const float* __restrict__ x,  const float* __restrict__ qw,
                        const float* __restrict__ kw, const float* __restrict__ vw,
                        const float* __restrict__ ow,
                        unsigned short* __restrict__ xb,  unsigned short* __restrict__ wqb,
                        unsigned short* __restrict__ wkb, unsigned short* __restrict__ wvb,
                        unsigned short* __restrict__ wob,
                        int n4x, int n4w){
  int i = blockIdx.x * 256 + threadIdx.x;
  const float* src; unsigned short* dst; int n4;
  switch (blockIdx.y) {
    case 0:  src = x;  dst = xb;  n4 = n4x; break;
    case 1:  src = qw; dst = wqb; n4 = n4w; break;
    case 2:  src = kw; dst = wkb; n4 = n4w; break;
    case 3:  src = vw; dst = wvb; n4 = n4w; break;
    default: src = ow; dst = wob; n4 = n4w; break;
  }
  if (i >= n4) return;
  float4 f = reinterpret_cast<const float4*>(src)[i];
  ushort4 u;
  u.x = f2bf(f.x); u.y = f2bf(f.y); u.z = f2bf(f.z); u.w = f2bf(f.w);
  reinterpret_cast<ushort4*>(dst)[i] = u;
}

// ---------------- FUSED QKV projection (one pass over X, R3 exact) ----------
// One block computes the 128x64 output tile for ALL THREE projections:
// stages its X-tile ONCE + Wq/Wk/Wv tiles.  Per K-step per wave: 48 MFMA,
// 20 ds_read_b128, 10 global_load_lds.  LDS 80 KB -> 2 blocks/CU; grid 512.
// Chunk-XOR swizzle (conflict-free, verified R1) + depth-2 counted-vmcnt
// pipeline (verified R2).  Scalar epilogue (lane-contiguous d): R7's packed
// uint2 stores with lane->(b,s) were 128B-stride scattered, cost ~4 us.
struct FragsQKV { short8 a0[4], a1[4], b0[3][2], b1[3][2]; };

__global__ __launch_bounds__(256, 2) void gemm_qkv(
    const unsigned short* __restrict__ X,
    const unsigned short* __restrict__ Wq,
    const unsigned short* __restrict__ Wk,
    const unsigned short* __restrict__ Wv,
    unsigned short* __restrict__ Qo,
    unsigned short* __restrict__ Ko,
    unsigned short* __restrict__ Vo)
{
  const int n0 = blockIdx.x * 64;
  const int m0 = blockIdx.y * 128;

  __shared__ unsigned short As[2][128 * 64];      // 2 x 16 KiB
  __shared__ unsigned short Bs[2][3][64 * 64];    // 2 x 3 x 8 KiB

  const int tid  = threadIdx.x;
  const int wid  = tid >> 6, lane = tid & 63;
  const int wm   = (wid >> 1) * 64, wn = (wid & 1) * 32;
  const int lr   = lane & 15, c = lane >> 4;
  const int sw   = lr & 7;
  const int pc0  = (c ^ sw) * 8;               // k-half 0 chunk, shorts
  const int pc1  = ((c ^ 4) ^ sw) * 8;         // k-half 1 chunk, shorts

  const int srow = lane >> 3;                  // 0..7
  const int scol = ((lane & 7) ^ srow) * 8;    // inverse-swizzled source col
  const unsigned short* gA  = X  + (size_t)(m0 + wid * 32 + srow) * KDIM + scol;
  const unsigned short* gBq = Wq + (size_t)(n0 + wid * 16 + srow) * KDIM + scol;
  const unsigned short* gBk = Wk + (size_t)(n0 + wid * 16 + srow) * KDIM + scol;
  const unsigned short* gBv = Wv + (size_t)(n0 + wid * 16 + srow) * KDIM + scol;

  auto stage = [&](int buf, int k0) {
    unsigned short* la  = &As[buf][(wid * 32) * 64];
    unsigned short* lbq = &Bs[buf][0][(wid * 16) * 64];
    unsigned short* lbk = &Bs[buf][1][(wid * 16) * 64];
    unsigned short* lbv = &Bs[buf][2][(wid * 16) * 64];
#pragma unroll
    for (int i = 0; i < 4; i++) gll16(gA + (size_t)(i * 8) * KDIM + k0, la + i * 512);
#pragma unroll
    for (int i = 0; i < 2; i++) gll16(gBq + (size_t)(i * 8) * KDIM + k0, lbq + i * 512);
#pragma unroll
    for (int i = 0; i < 2; i++) gll16(gBk + (size_t)(i * 8) * KDIM + k0, lbk + i * 512);
#pragma unroll
    for (int i = 0; i < 2; i++) gll16(gBv + (size_t)(i * 8) * KDIM + k0, lbv + i * 512);
  };

  auto ldfr = [&](int buf, FragsQKV& f) {
    const unsigned short* AS = As[buf];
#pragma unroll
    for (int i = 0; i < 4; i++) {
      f.a0[i] = *(const short8*)&AS[(wm + i * 16 + lr) * 64 + pc0];
      f.a1[i] = *(const short8*)&AS[(wm + i * 16 + lr) * 64 + pc1];
    }
#pragma unroll
    for (int z = 0; z < 3; z++) {
      const unsigned short* BS = Bs[buf][z];
#pragma unroll
      for (int j = 0; j < 2; j++) {
        f.b0[z][j] = *(const short8*)&BS[(wn + j * 16 + lr) * 64 + pc0];
        f.b1[z][j] = *(const short8*)&BS[(wn + j * 16 + lr) * 64 + pc1];
      }
    }
  };

  f32x4 acc[3][4][2];
  const f32x4 z4 = {0.f, 0.f, 0.f, 0.f};
#pragma unroll
  for (int z = 0; z < 3; z++)
    for (int i = 0; i < 4; i++)
      for (int j = 0; j < 2; j++) acc[z][i][j] = z4;

  auto mfmas = [&](const FragsQKV& f) {
#pragma unroll
    for (int z = 0; z < 3; z++) {
      if (z == 2) {
#pragma unroll
        for (int i = 0; i < 4; i++)
#pragma unroll
          for (int j = 0; j < 2; j++) {
            acc[z][i][j] = MFMA(f.b0[z][j], f.a0[i], acc[z][i][j]);  // V: rows=W-dim
            acc[z][i][j] = MFMA(f.b1[z][j], f.a1[i], acc[z][i][j]);
          }
      } else {
#pragma unroll
        for (int i = 0; i < 4; i++)
#pragma unroll
          for (int j = 0; j < 2; j++) {
            acc[z][i][j] = MFMA(f.a0[i], f.b0[z][j], acc[z][i][j]);
            acc[z][i][j] = MFMA(f.a1[i], f.b1[z][j], acc[z][i][j]);
          }
      }
    }
  };

  // prologue: two tiles in flight (20 loads)
  stage(0, 0);
  stage(1, 64);

  FragsQKV f;
  const int NT = KDIM / 64;                    // 16
  for (int t = 0; t < NT - 2; ++t) {
    const int buf = t & 1;
    asm volatile("s_waitcnt vmcnt(10)" ::: "memory");  // my stage(t) landed
    __builtin_amdgcn_s_barrier();                       // everyone's landed
    asm volatile("" ::: "memory");
    ldfr(buf, f);
    asm volatile("s_waitcnt lgkmcnt(0)" ::: "memory"); // my reads serviced
    __builtin_amdgcn_sched_barrier(0);
    __builtin_amdgcn_s_barrier();                       // buf free to overwrite
    asm volatile("" ::: "memory");
    stage(buf, (t + 2) * 64);                           // 10 loads in flight
    __builtin_amdgcn_sched_barrier(0);
    mfmas(f);                                           // covers load latency
  }
  // t = NT-2: no further staging
  asm volatile("s_waitcnt vmcnt(10)" ::: "memory");
  __builtin_amdgcn_s_barrier();
  asm volatile("" ::: "memory");
  ldfr((NT - 2) & 1, f);
  mfmas(f);
  // t = NT-1: drain the last tile
  asm volatile("s_waitcnt vmcnt(0)" ::: "memory");
  __builtin_amdgcn_s_barrier();
  asm volatile("" ::: "memory");
  ldfr((NT - 1) & 1, f);
  mfmas(f);

  const int rbase = (lane >> 4) * 4;
  // z=0: Q (scaled), z=1: K, z=2: V^T
  for (int i = 0; i < 4; i++)
    for (int j = 0; j < 2; j++)
      for (int r = 0; r < 4; r++) {
        int m = m0 + wm + i * 16 + rbase + r;
        int n = n0 + wn + j * 16 + lr;
        int bb = m >> 11, s = m & 2047, h = n >> 6, d = n & 63;
        float vq = acc[0][i][j][r] * 0.18033688f;  // (1/sqrt(64))*log2(e)
        Qo[(((bb * H_ + h) * S_) + s) * DK + d] = f2bf(vq);
        Ko[(((bb * H_ + h) * S_) + s) * DK + d] = f2bf(acc[1][i][j][r]);
      }
  for (int i = 0; i < 4; i++)
    for (int j = 0; j < 2; j++)
      for (int r = 0; r < 4; r++) {
        int dfull = n0 + wn + j * 16 + rbase + r;   // W row (h,dk)
        int sfull = m0 + wm + i * 16 + lr;          // X row (b,s)
        int h = dfull >> 6, d = dfull & 63;
        int bb = sfull >> 11, s = sfull & 2047;
        Vo[(((bb * H_ + h) * DK) + d) * S_ + s] = f2bf(acc[2][i][j][r]);
      }
}

// ---------------- causal flash attention (R8: in-register P, no Ps LDS) -----
// Q,K: [B,H,S,DK] bf16 (Q pre-scaled to exp2 domain); V: [B,H,DK,S] bf16.
// R3 structure (8 waves, 16 q-rows/wave, ping-pong, setprio) with the P
// round-trip ELIMINATED: QK MFMA m loads K rows 8*(i>>2)+4*(m&1)+(i&3)
// +32*(m>>1) (lane i), so output lane-group c, reg r holds key
// 8c+4*(m&1)+32*(m>>1)+r -- exactly the packed-key layout PV's B-operand
// needs.  pf0 = pack(exp sc0, exp sc1), pf1 = pack(exp sc2, exp sc3): all
// in-lane, zero cross-lane ops, Ps buffer deleted (LDS 50.4 -> 32 KB).
// K tile uses rotation sigma(row) = (row&7) + 2*((row>>3)&3): per 16-lane
// phase each 16B chunk-column is hit by exactly 2 lanes (free 2-way).
// V tile keeps the old row&7 rotation (read pattern unchanged).
__global__ __launch_bounds__(512, 4) void attn(
    const unsigned short* __restrict__ Q,
    const unsigned short* __restrict__ K,
    const unsigned short* __restrict__ V,
    unsigned short* __restrict__ O)
{
  const int h = blockIdx.y, b = blockIdx.z;
  const int qt = b ? (15 - blockIdx.x) : blockIdx.x;

  const unsigned short* __restrict__ Qh = Q + (size_t)((b * H_ + h) * S_) * DK;
  const unsigned short* __restrict__ Kh = K + (size_t)((b * H_ + h) * S_) * DK;
  const unsigned short* __restrict__ Vh = V + (size_t)((b * H_ + h) * DK) * S_;

  __shared__ unsigned short Ks0[64 * 64];     // [key][d], sigma-swizzled chunks
  __shared__ unsigned short Ks1[64 * 64];
  __shared__ unsigned short Vs0[64 * 64];     // [d][key], row&7-swizzled chunks
  __shared__ unsigned short Vs1[64 * 64];

  const int tid = threadIdx.x, wid = tid >> 6, lane = tid & 63;
  const int lr = lane & 15, c = lane >> 4;
  const int row4 = c * 4;
  const int q0 = qt * 128;
  const int qcol = q0 + wid * 16 + lr;
  const int qwmin = q0 + wid * 16;
  const int qwmax = qwmin + 15;
  const int lk = c * 8;                       // Q fragment k-offset

  // V read offsets (old rotation: phys chunk = (logical + row)&7, row=lr pattern)
  const int pcV0 = ((c + lr) & 7) * 8;
  const int pcV1 = ((c + 4 + lr) & 7) * 8;
  // K read offsets (sigma rotation).  s = sigma(row) for the m-even rows.
  const int s8 = (lr & 3) + 2 * (lr >> 2);
  const int pcA = ((c + s8) & 7) * 8;
  const int pcB = ((c + s8 + 4) & 7) * 8;
  const int rowb = (8 * (lr >> 2) + (lr & 3)) * 64;   // m0 row base, shorts

  // staging: wave wid covers rows [8*wid, 8*wid+8) of both K and V tiles
  const int sr8 = lane >> 3;                  // row within 8-row group
  const int sc8 = lane & 7;                   // physical chunk
  const int sgV = (sc8 - sr8) & 7;                    // V: rot = row&7
  const int sgK = (sc8 - sr8 - 2 * (wid & 3)) & 7;    // K: rot = sr8 + 2*(wid&3)
  const int stRow = wid * 8 + sr8;            // 0..63
  const unsigned short* gK = Kh + (size_t)stRow * DK + sgK * 8;
  const unsigned short* gV = Vh + (size_t)stRow * S_ + sgV * 8;
  unsigned short* lK0 = &Ks0[wid * 8 * 64];
  unsigned short* lK1 = &Ks1[wid * 8 * 64];
  unsigned short* lV0 = &Vs0[wid * 8 * 64];
  unsigned short* lV1 = &Vs1[wid * 8 * 64];

  const short ONE = (short)0x3F80;            // bf16 1.0
  const short8 ones = {ONE, ONE, ONE, ONE, ONE, ONE, ONE, ONE};

  short8 qf[2];
  qf[0] = *(const short8*)&Qh[(q0 + wid * 16 + lr) * DK + lk];
  qf[1] = *(const short8*)&Qh[(q0 + wid * 16 + lr) * DK + 32 + lk];

  const f32x4 z4 = {0.f, 0.f, 0.f, 0.f};
  f32x4 o[4];
  for (int i = 0; i < 4; i++) o[i] = z4;
  f32x4 rs = z4;                              // l(q=lr) on the MFMA pipe

  auto tile = [&](int k0, const unsigned short* KS, const unsigned short* VS){
    if (k0 > qwmax) return;                   // wave-uniform skip
    f32x4 sc[4];
    __builtin_amdgcn_s_setprio(1);
    {
      short8 kb;
      kb = *(const short8*)&KS[rowb + pcA];                 // m0 d-lo
      f32x4 t0 = MFMA(kb, qf[0], z4);
      kb = *(const short8*)&KS[rowb + pcB];                 // m0 d-hi
      sc[0] = MFMA(kb, qf[1], t0);
      kb = *(const short8*)&KS[rowb + 256 + pcB];           // m1 d-lo
      f32x4 t1 = MFMA(kb, qf[0], z4);
      kb = *(const short8*)&KS[rowb + 256 + pcA];           // m1 d-hi
      sc[1] = MFMA(kb, qf[1], t1);
      kb = *(const short8*)&KS[rowb + 2048 + pcA];          // m2 d-lo
      f32x4 t2 = MFMA(kb, qf[0], z4);
      kb = *(const short8*)&KS[rowb + 2048 + pcB];          // m2 d-hi
      sc[2] = MFMA(kb, qf[1], t2);
      kb = *(const short8*)&KS[rowb + 2304 + pcB];          // m3 d-lo
      f32x4 t3 = MFMA(kb, qf[0], z4);
      kb = *(const short8*)&KS[rowb + 2304 + pcA];          // m3 d-hi
      sc[3] = MFMA(kb, qf[1], t3);
    }
    __builtin_amdgcn_s_setprio(0);
    if (k0 + 63 > qwmin) {                    // diagonal region: mask key > q
#pragma unroll
      for (int m = 0; m < 4; m++) {
        int kg = k0 + 8 * c + 4 * (m & 1) + 32 * (m >> 1);
#pragma unroll
        for (int r = 0; r < 4; r++)
          if (kg + r > qcol) sc[m][r] = -INFINITY;
      }
    }
    u32 w[4][2];
#pragma unroll
    for (int m = 0; m < 4; m++) {
      float e0 = __builtin_amdgcn_exp2f(sc[m][0]);
      float e1 = __builtin_amdgcn_exp2f(sc[m][1]);
      float e2 = __builtin_amdgcn_exp2f(sc[m][2]);
      float e3 = __builtin_amdgcn_exp2f(sc[m][3]);
      w[m][0] = pkbf(e0, e1);
      w[m][1] = pkbf(e2, e3);
    }
    short8 pf0, pf1;
    {
      u32x4 a0 = {w[0][0], w[0][1], w[1][0], w[1][1]};  // keys 8c+0..7
      u32x4 a1 = {w[2][0], w[2][1], w[3][0], w[3][1]};  // keys 32+8c+0..7
      pf0 = *(short8*)&a0;
      pf1 = *(short8*)&a1;
    }
    __builtin_amdgcn_s_setprio(1);
    rs = MFMA(ones, pf0, rs);
    rs = MFMA(ones, pf1, rs);
#pragma unroll
    for (int dt = 0; dt < 4; dt++) {
      short8 vb0 = *(const short8*)&VS[(dt * 16 + lr) * 64 + pcV0];
      short8 vb1 = *(const short8*)&VS[(dt * 16 + lr) * 64 + pcV1];
      o[dt] = MFMA(vb0, pf0, o[dt]);
      o[dt] = MFMA(vb1, pf1, o[dt]);
    }
    __builtin_amdgcn_s_setprio(0);
  };

  const int kt_end = 2 * qt + 2;              // even

  // prologue: tile 0 into buf0
  gll16(gK, lK0);
  gll16(gV, lV0);

  for (int kt = 0; kt < kt_end; kt += 2) {
    const int k0 = kt * 64;
    __syncthreads();                          // buf0 (k0) ready
    {                                         // kt+1 always < kt_end
      gll16(gK + (size_t)(k0 + 64) * DK, lK1);
      gll16(gV + (k0 + 64),              lV1);
    }
    tile(k0, Ks0, Vs0);
    __syncthreads();                          // buf1 (k0+64) ready
    if (kt + 2 < kt_end) {
      gll16(gK + (size_t)(k0 + 128) * DK, lK0);
      gll16(gV + (k0 + 128),              lV0);
    }
    tile(k0 + 64, Ks1, Vs1);
  }

  const float inv = 1.0f / rs[0];

  const int srow = q0 + wid * 16 + lr;
  for (int dt = 0; dt < 4; dt++) {
    uint2 pk;
    pk.x = pkbf(o[dt][0] * inv, o[dt][1] * inv);
    pk.y = pkbf(o[dt][2] * inv, o[dt][3] * inv);
    *(uint2*)&O[(size_t)(b * S_ + srow) * D_ + h * DK + dt * 16 + row4] = pk;
  }
}

struct Frags { short8 a0[4], a1[4], b0[2], b1[2]; };

// ---------------- output projection (counted-vmcnt pipeline, fp32 out) ------
__global__ __launch_bounds__(256) void gemm_oproj(
    const unsigned short* __restrict__ A,
    const unsigned short* __restrict__ W,
    float* __restrict__ out)
{
  const int n0 = blockIdx.x * 64;
  const int m0 = blockIdx.y * 128;

  __shared__ unsigned short As[2][128 * 64];
  __shared__ unsigned short Bs[2][64 * 64];

  const int tid  = threadIdx.x;
  const int wid  = tid >> 6, lane = tid & 63;
  const int wm   = (wid >> 1) * 64, wn = (wid & 1) * 32;
  const int lr   = lane & 15, c = lane >> 4;
  const int sw   = lr & 7;
  const int pc0  = (c ^ sw) * 8;
  const int pc1  = ((c ^ 4) ^ sw) * 8;

  const int srow = lane >> 3;
  const int scol = ((lane & 7) ^ srow) * 8;
  const unsigned short* gA = A + (size_t)(m0 + wid * 32 + srow) * KDIM + scol;
  const unsigned short* gB = W + (size_t)(n0 + wid * 16 + srow) * KDIM + scol;

  auto stage = [&](int buf, int k0) {
    unsigned short* la = &As[buf][(wid * 32) * 64];
    unsigned short* lb = &Bs[buf][(wid * 16) * 64];
#pragma unroll
    for (int i = 0; i < 4; i++) gll16(gA + (size_t)(i * 8) * KDIM + k0, la + i * 512);
#pragma unroll
    for (int i = 0; i < 2; i++) gll16(gB + (size_t)(i * 8) * KDIM + k0, lb + i * 512);
  };

  auto ldfr = [&](int buf, Frags& f) {
    const unsigned short* AS = As[buf];
    const unsigned short* BS = Bs[buf];
#pragma unroll
    for (int i = 0; i < 4; i++) {
      f.a0[i] = *(const short8*)&AS[(wm + i * 16 + lr) * 64 + pc0];
      f.a1[i] = *(const short8*)&AS[(wm + i * 16 + lr) * 64 + pc1];
    }
#pragma unroll
    for (int j = 0; j < 2; j++) {
      f.b0[j] = *(const short8*)&BS[(wn + j * 16 + lr) * 64 + pc0];
      f.b1[j] = *(const short8*)&BS[(wn + j * 16 + lr) * 64 + pc1];
    }
  };

  f32x4 acc[4][2];
  const f32x4 z4 = {0.f, 0.f, 0.f, 0.f};
  for (int i = 0; i < 4; i++)
    for (int j = 0; j < 2; j++) acc[i][j] = z4;

  auto mfmas = [&](const Frags& f) {
#pragma unroll
    for (int i = 0; i < 4; i++)
#pragma unroll
      for (int j = 0; j < 2; j++) {
        acc[i][j] = MFMA(f.a0[i], f.b0[j], acc[i][j]);
        acc[i][j] = MFMA(f.a1[i], f.b1[j], acc[i][j]);
      }
  };

  stage(0, 0);
  stage(1, 64);

  Frags f;
  const int NT = KDIM / 64;                    // 16
  for (int t = 0; t < NT - 2; ++t) {
    const int buf = t & 1;
    asm volatile("s_waitcnt vmcnt(6)" ::: "memory");
    __builtin_amdgcn_s_barrier();
    asm volatile("" ::: "memory");
    ldfr(buf, f);
    asm volatile("s_waitcnt lgkmcnt(0)" ::: "memory");
    __builtin_amdgcn_sched_barrier(0);
    __builtin_amdgcn_s_barrier();
    asm volatile("" ::: "memory");
    stage(buf, (t + 2) * 64);
    __builtin_amdgcn_sched_barrier(0);
    mfmas(f);
  }
  asm volatile("s_waitcnt vmcnt(6)" ::: "memory");
  __builtin_amdgcn_s_barrier();
  asm volatile("" ::: "memory");
  ldfr((NT - 2) & 1, f);
  mfmas(f);
  asm volatile("s_waitcnt vmcnt(0)" ::: "memory");
  __builtin_amdgcn_s_barrier();
  asm volatile("" ::: "memory");
  ldfr((NT - 1) & 1, f);
  mfmas(f);

  const int rbase = (lane >> 4) * 4;
  for (int i = 0; i < 4; i++)
    for (int j = 0; j < 2; j++)
      for (int r = 0; r < 4; r++) {
        int m = m0 + wm + i * 16 + rbase + r;
        int n = n0 + wn + j * 16 + lr;
        out[(size_t)m * D_ + n] = acc[i][j][r];
      }
}

extern "C" void kernel_launch(void* const* d_in, const int* in_sizes, int n_in,
                              void* d_out, int out_size, void* d_ws, size_t ws_size,
                              hipStream_t stream) {
  const float* x  = (const float*)d_in[0];
  const float* qw = (const float*)d_in[1];
  const float* kw = (const float*)d_in[2];
  const float* vw = (const float*)d_in[3];
  const float* ow = (const float*)d_in[4];
  float* out = (float*)d_out;

  char* ws = (char*)d_ws;
  size_t off = 0;
  auto alloc = [&](size_t bytes) -> void* {
    void* p = ws + off;
    off += (bytes + 255) & ~(size_t)255;
    return p;
  };
  const size_t XN = (size_t)B_ * S_ * D_;     // 4194304
  const size_t WN = (size_t)D_ * D_;          // 1048576
  unsigned short* xb  = (unsigned short*)alloc(XN * 2);
  unsigned short* wqb = (unsigned short*)alloc(WN * 2);
  unsigned short* wkb = (unsigned short*)alloc(WN * 2);
  unsigned short* wvb = (unsigned short*)alloc(WN * 2);
  unsigned short* wob = (unsigned short*)alloc(WN * 2);
  unsigned short* Qb  = (unsigned short*)alloc(XN * 2);
  unsigned short* Kb  = (unsigned short*)alloc(XN * 2);
  unsigned short* Vb  = (unsigned short*)alloc(XN * 2);
  unsigned short* Ob  = (unsigned short*)alloc(XN * 2);

  cvt_all<<<dim3((XN / 4 + 255) / 256, 5), dim3(256), 0, stream>>>(
      x, qw, kw, vw, ow, xb, wqb, wkb, wvb, wob, (int)(XN / 4), (int)(WN / 4));

  gemm_qkv<<<dim3(D_ / 64, (B_ * S_) / 128), dim3(256), 0, stream>>>(
      xb, wqb, wkb, wvb, Qb, Kb, Vb);

  attn<<<dim3(S_ / 128, H_, B_), dim3(512), 0, stream>>>(Qb, Kb, Vb, Ob);

  gemm_oproj<<<dim3(D_ / 64, (B_ * S_) / 128), dim3(256), 0, stream>>>(Ob, wob, out);
}

// Round 9
// 153.302 us; speedup vs baseline: 1.0527x; 1.0058x over previous
//
#include <hip/hip_runtime.h>

typedef __attribute__((ext_vector_type(8))) short short8;
typedef __attribute__((ext_vector_type(4))) float f32x4;
typedef __attribute__((ext_vector_type(4))) unsigned int u32x4;

#define MFMA(a,b,c) __builtin_amdgcn_mfma_f32_16x16x32_bf16((a),(b),(c),0,0,0)

#define B_  2
#define S_  2048
#define D_  1024
#define H_  16
#define DK  64
#define KDIM 1024

typedef unsigned int u32;
typedef __attribute__((address_space(1))) const u32 gu32;
typedef __attribute__((address_space(3))) u32 lu32;

// async global->LDS, 16 B per lane; LDS dest = base + lane*16 (wave-uniform base)
__device__ __forceinline__ void gll16(const unsigned short* g, unsigned short* l){
  __builtin_amdgcn_global_load_lds((gu32*)g, (lu32*)l, 16, 0, 0);
}

__device__ __forceinline__ unsigned short f2bf(float f){
  unsigned int u = __float_as_uint(f);
  u += 0x7fffu + ((u >> 16) & 1u);   // RNE (finite inputs only)
  return (unsigned short)(u >> 16);
}

// pack two f32 -> two bf16 (round-half-up) in 3 VALU: 2 adds + v_perm_b32.
__device__ __forceinline__ u32 pkbf(float lo, float hi){
  u32 a = __float_as_uint(lo) + 0x8000u;
  u32 b = __float_as_uint(hi) + 0x8000u;
  return __builtin_amdgcn_perm(b, a, 0x07060302u);
}

// ---------------- fp32 -> bf16 convert, all 5 tensors in one launch ---------
__global__ void cvt_all(const float* __restrict__ x,  const float* __restrict__ qw,
                        const float* __restrict__ kw, const float* __restrict__ vw,
                        const float* __restrict__ ow,
                        unsigned short* __restrict__ xb,  unsigned short* __restrict__ wqb,
                        unsigned short* __restrict__ wkb, unsigned short* __restrict__ wvb,
                        unsigned short* __restrict__ wob,
                        int n4x, int n4w){
  int i = blockIdx.x * 256 + threadIdx.x;
  const float* src; unsigned short* dst; int n4;
  switch (blockIdx.y) {
    case 0:  src = x;  dst = xb;  n4 = n4x; break;
    case 1:  src = qw; dst = wqb; n4 = n4w; break;
    case 2:  src = kw; dst = wkb; n4 = n4w; break;
    case 3:  src = vw; dst = wvb; n4 = n4w; break;
    default: src = ow; dst = wob; n4 = n4w; break;
  }
  if (i >= n4) return;
  float4 f = reinterpret_cast<const float4*>(src)[i];
  ushort4 u;
  u.x = f2bf(f.x); u.y = f2bf(f.y); u.z = f2bf(f.z); u.w = f2bf(f.w);
  reinterpret_cast<ushort4*>(dst)[i] = u;
}

// ---------------- FUSED QKV projection (one pass over X, R3 exact) ----------
struct FragsQKV { short8 a0[4], a1[4], b0[3][2], b1[3][2]; };

__global__ __launch_bounds__(256, 2) void gemm_qkv(
    const unsigned short* __restrict__ X,
    const unsigned short* __restrict__ Wq,
    const unsigned short* __restrict__ Wk,
    const unsigned short* __restrict__ Wv,
    unsigned short* __restrict__ Qo,
    unsigned short* __restrict__ Ko,
    unsigned short* __restrict__ Vo)
{
  const int n0 = blockIdx.x * 64;
  const int m0 = blockIdx.y * 128;

  __shared__ unsigned short As[2][128 * 64];      // 2 x 16 KiB
  __shared__ unsigned short Bs[2][3][64 * 64];    // 2 x 3 x 8 KiB

  const int tid  = threadIdx.x;
  const int wid  = tid >> 6, lane = tid & 63;
  const int wm   = (wid >> 1) * 64, wn = (wid & 1) * 32;
  const int lr   = lane & 15, c = lane >> 4;
  const int sw   = lr & 7;
  const int pc0  = (c ^ sw) * 8;               // k-half 0 chunk, shorts
  const int pc1  = ((c ^ 4) ^ sw) * 8;         // k-half 1 chunk, shorts

  const int srow = lane >> 3;                  // 0..7
  const int scol = ((lane & 7) ^ srow) * 8;    // inverse-swizzled source col
  const unsigned short* gA  = X  + (size_t)(m0 + wid * 32 + srow) * KDIM + scol;
  const unsigned short* gBq = Wq + (size_t)(n0 + wid * 16 + srow) * KDIM + scol;
  const unsigned short* gBk = Wk + (size_t)(n0 + wid * 16 + srow) * KDIM + scol;
  const unsigned short* gBv = Wv + (size_t)(n0 + wid * 16 + srow) * KDIM + scol;

  auto stage = [&](int buf, int k0) {
    unsigned short* la  = &As[buf][(wid * 32) * 64];
    unsigned short* lbq = &Bs[buf][0][(wid * 16) * 64];
    unsigned short* lbk = &Bs[buf][1][(wid * 16) * 64];
    unsigned short* lbv = &Bs[buf][2][(wid * 16) * 64];
#pragma unroll
    for (int i = 0; i < 4; i++) gll16(gA + (size_t)(i * 8) * KDIM + k0, la + i * 512);
#pragma unroll
    for (int i = 0; i < 2; i++) gll16(gBq + (size_t)(i * 8) * KDIM + k0, lbq + i * 512);
#pragma unroll
    for (int i = 0; i < 2; i++) gll16(gBk + (size_t)(i * 8) * KDIM + k0, lbk + i * 512);
#pragma unroll
    for (int i = 0; i < 2; i++) gll16(gBv + (size_t)(i * 8) * KDIM + k0, lbv + i * 512);
  };

  auto ldfr = [&](int buf, FragsQKV& f) {
    const unsigned short* AS = As[buf];
#pragma unroll
    for (int i = 0; i < 4; i++) {
      f.a0[i] = *(const short8*)&AS[(wm + i * 16 + lr) * 64 + pc0];
      f.a1[i] = *(const short8*)&AS[(wm + i * 16 + lr) * 64 + pc1];
    }
#pragma unroll
    for (int z = 0; z < 3; z++) {
      const unsigned short* BS = Bs[buf][z];
#pragma unroll
      for (int j = 0; j < 2; j++) {
        f.b0[z][j] = *(const short8*)&BS[(wn + j * 16 + lr) * 64 + pc0];
        f.b1[z][j] = *(const short8*)&BS[(wn + j * 16 + lr) * 64 + pc1];
      }
    }
  };

  f32x4 acc[3][4][2];
  const f32x4 z4 = {0.f, 0.f, 0.f, 0.f};
#pragma unroll
  for (int z = 0; z < 3; z++)
    for (int i = 0; i < 4; i++)
      for (int j = 0; j < 2; j++) acc[z][i][j] = z4;

  auto mfmas = [&](const FragsQKV& f) {
#pragma unroll
    for (int z = 0; z < 3; z++) {
      if (z == 2) {
#pragma unroll
        for (int i = 0; i < 4; i++)
#pragma unroll
          for (int j = 0; j < 2; j++) {
            acc[z][i][j] = MFMA(f.b0[z][j], f.a0[i], acc[z][i][j]);  // V: rows=W-dim
            acc[z][i][j] = MFMA(f.b1[z][j], f.a1[i], acc[z][i][j]);
          }
      } else {
#pragma unroll
        for (int i = 0; i < 4; i++)
#pragma unroll
          for (int j = 0; j < 2; j++) {
            acc[z][i][j] = MFMA(f.a0[i], f.b0[z][j], acc[z][i][j]);
            acc[z][i][j] = MFMA(f.a1[i], f.b1[z][j], acc[z][i][j]);
          }
      }
    }
  };

  // prologue: two tiles in flight (20 loads)
  stage(0, 0);
  stage(1, 64);

  FragsQKV f;
  const int NT = KDIM / 64;                    // 16
  for (int t = 0; t < NT - 2; ++t) {
    const int buf = t & 1;
    asm volatile("s_waitcnt vmcnt(10)" ::: "memory");  // my stage(t) landed
    __builtin_amdgcn_s_barrier();                       // everyone's landed
    asm volatile("" ::: "memory");
    ldfr(buf, f);
    asm volatile("s_waitcnt lgkmcnt(0)" ::: "memory"); // my reads serviced
    __builtin_amdgcn_sched_barrier(0);
    __builtin_amdgcn_s_barrier();                       // buf free to overwrite
    asm volatile("" ::: "memory");
    stage(buf, (t + 2) * 64);                           // 10 loads in flight
    __builtin_amdgcn_sched_barrier(0);
    mfmas(f);                                           // covers load latency
  }
  // t = NT-2: no further staging
  asm volatile("s_waitcnt vmcnt(10)" ::: "memory");
  __builtin_amdgcn_s_barrier();
  asm volatile("" ::: "memory");
  ldfr((NT - 2) & 1, f);
  mfmas(f);
  // t = NT-1: drain the last tile
  asm volatile("s_waitcnt vmcnt(0)" ::: "memory");
  __builtin_amdgcn_s_barrier();
  asm volatile("" ::: "memory");
  ldfr((NT - 1) & 1, f);
  mfmas(f);

  const int rbase = (lane >> 4) * 4;
  // z=0: Q (scaled), z=1: K, z=2: V^T
  for (int i = 0; i < 4; i++)
    for (int j = 0; j < 2; j++)
      for (int r = 0; r < 4; r++) {
        int m = m0 + wm + i * 16 + rbase + r;
        int n = n0 + wn + j * 16 + lr;
        int bb = m >> 11, s = m & 2047, h = n >> 6, d = n & 63;
        float vq = acc[0][i][j][r] * 0.18033688f;  // (1/sqrt(64))*log2(e)
        Qo[(((bb * H_ + h) * S_) + s) * DK + d] = f2bf(vq);
        Ko[(((bb * H_ + h) * S_) + s) * DK + d] = f2bf(acc[1][i][j][r]);
      }
  for (int i = 0; i < 4; i++)
    for (int j = 0; j < 2; j++)
      for (int r = 0; r < 4; r++) {
        int dfull = n0 + wn + j * 16 + rbase + r;   // W row (h,dk)
        int sfull = m0 + wm + i * 16 + lr;          // X row (b,s)
        int h = dfull >> 6, d = dfull & 63;
        int bb = sfull >> 11, s = sfull & 2047;
        Vo[(((bb * H_ + h) * DK) + d) * S_ + s] = f2bf(acc[2][i][j][r]);
      }
}

// ---------------- causal flash attention (R9: KVBLK=128, in-register P) -----
// Q,K: [B,H,S,DK] bf16 (Q pre-scaled to exp2 domain); V: [B,H,DK,S] bf16.
// 128-key steps: 36 MFMAs (16 QK + 4 rs + 16 PV) and 4 gll16 per step with
// ONE barrier -- half the barrier/drain count of the 64-key version, double
// the prefetch cover.  In-register P (R8-verified): QK MFMA m loads K rows
// 8*(i>>2)+(i&3)+4*(m&1)+32*(m>>1), so lane-group c reg r holds key
// 8c+4*(m&1)+32*(m>>1)+r -- the packed-key layout PV's B-operand needs.
// K tile [128][64]: sigma(row)=(row&7)+2*((row>>3)&3) chunk rotation
// (invariant under row+32 -> read offsets unchanged from R8; 2-way = free).
// V tile [64][128]: phys16 = (logical+row)&15 rotation; read chunk collapses
// to (4j+c+lr)&15 (per-lane constant; 16 distinct chunks/phase = free).
// LDS 64 KB, ping-pong, __syncthreads per step, setprio on MFMA clusters.
__global__ __launch_bounds__(512, 4) void attn(
    const unsigned short* __restrict__ Q,
    const unsigned short* __restrict__ K,
    const unsigned short* __restrict__ V,
    unsigned short* __restrict__ O)
{
  const int h = blockIdx.y, b = blockIdx.z;
  const int qt = b ? (15 - blockIdx.x) : blockIdx.x;

  const unsigned short* __restrict__ Qh = Q + (size_t)((b * H_ + h) * S_) * DK;
  const unsigned short* __restrict__ Kh = K + (size_t)((b * H_ + h) * S_) * DK;
  const unsigned short* __restrict__ Vh = V + (size_t)((b * H_ + h) * DK) * S_;

  __shared__ unsigned short Ks0[128 * 64];    // [key][d], sigma-rotated chunks
  __shared__ unsigned short Ks1[128 * 64];
  __shared__ unsigned short Vs0[64 * 128];    // [d][key], 16-chunk-rotated
  __shared__ unsigned short Vs1[64 * 128];

  const int tid = threadIdx.x, wid = tid >> 6, lane = tid & 63;
  const int lr = lane & 15, c = lane >> 4;
  const int row4 = c * 4;
  const int q0 = qt * 128;
  const int qcol = q0 + wid * 16 + lr;
  const int lk = c * 8;                       // Q fragment k-offset

  // K read offsets (sigma rotation), verified R8
  const int s8 = (lr & 3) + 2 * (lr >> 2);
  const int pcA = ((c + s8) & 7) * 8;
  const int pcB = ((c + s8 + 4) & 7) * 8;
  const int rowb = (8 * (lr >> 2) + (lr & 3)) * 64;   // m0 row base, shorts
  // V read offsets: chunk (4j+c+lr)&15, constant per j
  int pcV[4];
#pragma unroll
  for (int j = 0; j < 4; j++) pcV[j] = ((4 * j + c + lr) & 15) * 8;

  // K staging: wave wid covers rows [16wid, 16wid+16), 2 gll16
  const int sr8 = lane >> 3;                  // row within 8-row group
  const int sc8 = lane & 7;                   // physical chunk
  const int sgK1 = (sc8 - sr8 - 2 * ((2 * wid) & 3)) & 7;
  const int sgK2 = (sc8 - sr8 - 2 * ((2 * wid + 1) & 3)) & 7;
  const unsigned short* gK1 = Kh + (size_t)(16 * wid + sr8) * DK + sgK1 * 8;
  const unsigned short* gK2 = Kh + (size_t)(16 * wid + 8 + sr8) * DK + sgK2 * 8;
  // V staging: wave wid covers rows [8wid, 8wid+8), 2 gll16 (4 rows each)
  const int vr = lane >> 4;                   // row within 4-row group
  const int vc16 = lane & 15;                 // physical chunk (16/row)
  const int sgV1 = (vc16 - (8 * wid + vr)) & 15;
  const int sgV2 = (sgV1 - 4) & 15;
  const unsigned short* gV1 = Vh + (size_t)(8 * wid + vr) * S_ + sgV1 * 8;
  const unsigned short* gV2 = Vh + (size_t)(8 * wid + 4 + vr) * S_ + sgV2 * 8;

  const short ONE = (short)0x3F80;            // bf16 1.0
  const short8 ones = {ONE, ONE, ONE, ONE, ONE, ONE, ONE, ONE};

  short8 qf[2];
  qf[0] = *(const short8*)&Qh[(q0 + wid * 16 + lr) * DK + lk];
  qf[1] = *(const short8*)&Qh[(q0 + wid * 16 + lr) * DK + 32 + lk];

  const f32x4 z4 = {0.f, 0.f, 0.f, 0.f};
  f32x4 o[4];
  for (int i = 0; i < 4; i++) o[i] = z4;
  f32x4 rs = z4;                              // l(q=lr) on the MFMA pipe

  auto stage = [&](int par, int k0) {
    unsigned short* lk_ = (par ? Ks1 : Ks0) + (wid * 16) * 64;
    unsigned short* lv_ = (par ? Vs1 : Vs0) + (wid * 8) * 128;
    gll16(gK1 + (size_t)k0 * DK, lk_);
    gll16(gK2 + (size_t)k0 * DK, lk_ + 512);
    gll16(gV1 + k0, lv_);
    gll16(gV2 + k0, lv_ + 512);
  };

  auto tile = [&](int k0, const unsigned short* KS, const unsigned short* VS,
                  bool diag) {
    short8 pf[4];
#pragma unroll
    for (int j = 0; j < 4; j++) {
      const int ro = rowb + j * 2048;
      short8 kb;
      __builtin_amdgcn_s_setprio(1);
      kb = *(const short8*)&KS[ro + pcA];                // m=2j   d-lo
      f32x4 ta = MFMA(kb, qf[0], z4);
      kb = *(const short8*)&KS[ro + pcB];                // m=2j   d-hi
      f32x4 sa = MFMA(kb, qf[1], ta);
      kb = *(const short8*)&KS[ro + 256 + pcB];          // m=2j+1 d-lo
      f32x4 tb = MFMA(kb, qf[0], z4);
      kb = *(const short8*)&KS[ro + 256 + pcA];          // m=2j+1 d-hi
      f32x4 sb = MFMA(kb, qf[1], tb);
      __builtin_amdgcn_s_setprio(0);
      if (diag) {
        const int kg = k0 + 8 * c + 32 * j;
#pragma unroll
        for (int r = 0; r < 4; r++) {
          if (kg + r > qcol)     sa[r] = -INFINITY;
          if (kg + 4 + r > qcol) sb[r] = -INFINITY;
        }
      }
      u32 w0 = pkbf(__builtin_amdgcn_exp2f(sa[0]), __builtin_amdgcn_exp2f(sa[1]));
      u32 w1 = pkbf(__builtin_amdgcn_exp2f(sa[2]), __builtin_amdgcn_exp2f(sa[3]));
      u32 w2 = pkbf(__builtin_amdgcn_exp2f(sb[0]), __builtin_amdgcn_exp2f(sb[1]));
      u32 w3 = pkbf(__builtin_amdgcn_exp2f(sb[2]), __builtin_amdgcn_exp2f(sb[3]));
      u32x4 a = {w0, w1, w2, w3};              // keys 32j + 8c .. 8c+8
      pf[j] = *(short8*)&a;
    }
    __builtin_amdgcn_s_setprio(1);
    rs = MFMA(ones, pf[0], rs);
    rs = MFMA(ones, pf[1], rs);
    rs = MFMA(ones, pf[2], rs);
    rs = MFMA(ones, pf[3], rs);
#pragma unroll
    for (int dt = 0; dt < 4; dt++) {
      const int rb2 = (dt * 16 + lr) * 128;
#pragma unroll
      for (int j = 0; j < 4; j++) {
        short8 vb = *(const short8*)&VS[rb2 + pcV[j]];
        o[dt] = MFMA(vb, pf[j], o[dt]);
      }
    }
    __builtin_amdgcn_s_setprio(0);
  };

  const int T = qt + 1;                       // 128-key steps

  stage(0, 0);
  for (int t = 0; t < T; ++t) {
    __syncthreads();                          // buf[t&1] loads landed (all waves)
    if (t + 1 < T) stage((t + 1) & 1, (t + 1) * 128);
    tile(t * 128, (t & 1) ? Ks1 : Ks0, (t & 1) ? Vs1 : Vs0, t == T - 1);
  }

  const float inv = 1.0f / rs[0];

  const int srow = q0 + wid * 16 + lr;
  for (int dt = 0; dt < 4; dt++) {
    uint2 pk;
    pk.x = pkbf(o[dt][0] * inv, o[dt][1] * inv);
    pk.y = pkbf(o[dt][2] * inv, o[dt][3] * inv);
    *(uint2*)&O[(size_t)(b * S_ + srow) * D_ + h * DK + dt * 16 + row4] = pk;
  }
}

struct Frags { short8 a0[4], a1[4], b0[2], b1[2]; };

// ---------------- output projection (counted-vmcnt pipeline, fp32 out) ------
__global__ __launch_bounds__(256) void gemm_oproj(
    const unsigned short* __restrict__ A,
    const unsigned short* __restrict__ W,
    float* __restrict__ out)
{
  const int n0 = blockIdx.x * 64;
  const int m0 = blockIdx.y * 128;

  __shared__ unsigned short As[2][128 * 64];
  __shared__ unsigned short Bs[2][64 * 64];

  const int tid  = threadIdx.x;
  const int wid  = tid >> 6, lane = tid & 63;
  const int wm   = (wid >> 1) * 64, wn = (wid & 1) * 32;
  const int lr   = lane & 15, c = lane >> 4;
  const int sw   = lr & 7;
  const int pc0  = (c ^ sw) * 8;
  const int pc1  = ((c ^ 4) ^ sw) * 8;

  const int srow = lane >> 3;
  const int scol = ((lane & 7) ^ srow) * 8;
  const unsigned short* gA = A + (size_t)(m0 + wid * 32 + srow) * KDIM + scol;
  const unsigned short* gB = W + (size_t)(n0 + wid * 16 + srow) * KDIM + scol;

  auto stage = [&](int buf, int k0) {
    unsigned short* la = &As[buf][(wid * 32) * 64];
    unsigned short* lb = &Bs[buf][(wid * 16) * 64];
#pragma unroll
    for (int i = 0; i < 4; i++) gll16(gA + (size_t)(i * 8) * KDIM + k0, la + i * 512);
#pragma unroll
    for (int i = 0; i < 2; i++) gll16(gB + (size_t)(i * 8) * KDIM + k0, lb + i * 512);
  };

  auto ldfr = [&](int buf, Frags& f) {
    const unsigned short* AS = As[buf];
    const unsigned short* BS = Bs[buf];
#pragma unroll
    for (int i = 0; i < 4; i++) {
      f.a0[i] = *(const short8*)&AS[(wm + i * 16 + lr) * 64 + pc0];
      f.a1[i] = *(const short8*)&AS[(wm + i * 16 + lr) * 64 + pc1];
    }
#pragma unroll
    for (int j = 0; j < 2; j++) {
      f.b0[j] = *(const short8*)&BS[(wn + j * 16 + lr) * 64 + pc0];
      f.b1[j] = *(const short8*)&BS[(wn + j * 16 + lr) * 64 + pc1];
    }
  };

  f32x4 acc[4][2];
  const f32x4 z4 = {0.f, 0.f, 0.f, 0.f};
  for (int i = 0; i < 4; i++)
    for (int j = 0; j < 2; j++) acc[i][j] = z4;

  auto mfmas = [&](const Frags& f) {
#pragma unroll
    for (int i = 0; i < 4; i++)
#pragma unroll
      for (int j = 0; j < 2; j++) {
        acc[i][j] = MFMA(f.a0[i], f.b0[j], acc[i][j]);
        acc[i][j] = MFMA(f.a1[i], f.b1[j], acc[i][j]);
      }
  };

  stage(0, 0);
  stage(1, 64);

  Frags f;
  const int NT = KDIM / 64;                    // 16
  for (int t = 0; t < NT - 2; ++t) {
    const int buf = t & 1;
    asm volatile("s_waitcnt vmcnt(6)" ::: "memory");
    __builtin_amdgcn_s_barrier();
    asm volatile("" ::: "memory");
    ldfr(buf, f);
    asm volatile("s_waitcnt lgkmcnt(0)" ::: "memory");
    __builtin_amdgcn_sched_barrier(0);
    __builtin_amdgcn_s_barrier();
    asm volatile("" ::: "memory");
    stage(buf, (t + 2) * 64);
    __builtin_amdgcn_sched_barrier(0);
    mfmas(f);
  }
  asm volatile("s_waitcnt vmcnt(6)" ::: "memory");
  __builtin_amdgcn_s_barrier();
  asm volatile("" ::: "memory");
  ldfr((NT - 2) & 1, f);
  mfmas(f);
  asm volatile("s_waitcnt vmcnt(0)" ::: "memory");
  __builtin_amdgcn_s_barrier();
  asm volatile("" ::: "memory");
  ldfr((NT - 1) & 1, f);
  mfmas(f);

  const int rbase = (lane >> 4) * 4;
  for (int i = 0; i < 4; i++)
    for (int j = 0; j < 2; j++)
      for (int r = 0; r < 4; r++) {
        int m = m0 + wm + i * 16 + rbase + r;
        int n = n0 + wn + j * 16 + lr;
        out[(size_t)m * D_ + n] = acc[i][j][r];
      }
}

extern "C" void kernel_launch(void* const* d_in, const int* in_sizes, int n_in,
                              void* d_out, int out_size, void* d_ws, size_t ws_size,
                              hipStream_t stream) {
  const float* x  = (const float*)d_in[0];
  const float* qw = (const float*)d_in[1];
  const float* kw = (const float*)d_in[2];
  const float* vw = (const float*)d_in[3];
  const float* ow = (const float*)d_in[4];
  float* out = (float*)d_out;

  char* ws = (char*)d_ws;
  size_t off = 0;
  auto alloc = [&](size_t bytes) -> void* {
    void* p = ws + off;
    off += (bytes + 255) & ~(size_t)255;
    return p;
  };
  const size_t XN = (size_t)B_ * S_ * D_;     // 4194304
  const size_t WN = (size_t)D_ * D_;          // 1048576
  unsigned short* xb  = (unsigned short*)alloc(XN * 2);
  unsigned short* wqb = (unsigned short*)alloc(WN * 2);
  unsigned short* wkb = (unsigned short*)alloc(WN * 2);
  unsigned short* wvb = (unsigned short*)alloc(WN * 2);
  unsigned short* wob = (unsigned short*)alloc(WN * 2);
  unsigned short* Qb  = (unsigned short*)alloc(XN * 2);
  unsigned short* Kb  = (unsigned short*)alloc(XN * 2);
  unsigned short* Vb  = (unsigned short*)alloc(XN * 2);
  unsigned short* Ob  = (unsigned short*)alloc(XN * 2);

  cvt_all<<<dim3((XN / 4 + 255) / 256, 5), dim3(256), 0, stream>>>(
      x, qw, kw, vw, ow, xb, wqb, wkb, wvb, wob, (int)(XN / 4), (int)(WN / 4));

  gemm_qkv<<<dim3(D_ / 64, (B_ * S_) / 128), dim3(256), 0, stream>>>(
      xb, wqb, wkb, wvb, Qb, Kb, Vb);

  attn<<<dim3(S_ / 128, H_, B_), dim3(512), 0, stream>>>(Qb, Kb, Vb, Ob);

  gemm_oproj<<<dim3(D_ / 64, (B_ * S_) / 128), dim3(256), 0, stream>>>(Ob, wob, out);
}